// Round 4
// baseline (70.114 us; speedup 1.0000x reference)
//
#include <hip/hip_runtime.h>

// GraphConvLayer on MI355X (gfx950). f32 I/O, bf16 inside MFMA.
// softmax_j(src_i+dst_j+b) over neighbors == e_j/sum(e)  (src_i, b cancel).
//   Bt[n][k]: n=b*64+f -> bf16(e_bj * X[b,j,f]) (k=j); n=4096+b -> bf16(e_bj)
//   Z = A_pad(896x832) @ Bt^T   -> Z[i][b*64+f] = agg_unnorm, Z[i][4096+b] = denom
//   out = relu(LN( [X | Z/den] @ [Ws|Wn]^T + bs + bn*(den>0) ))

typedef unsigned short u16;
typedef unsigned int u32;
typedef short bf16x8 __attribute__((ext_vector_type(8)));
typedef float f32x4 __attribute__((ext_vector_type(4)));

#define NNODE 784
#define MP 832      // K (padded node count)
#define MT 896      // padded rows of A / Z (7 x 128)
#define NPAD 4224   // padded cols of Z (33 x 128): 4096 feats + 64 denom + 64 pad
#define LDPG 72     // gemm LDS pitch (u16): row stride 144B -> conflict-free b128
#define LDPT 136    // tail LDS pitch (u16): row stride 272B

__device__ __forceinline__ float b2f(u16 h) {
  union { u32 u; float f; } v; v.u = ((u32)h) << 16; return v.f;
}
__device__ __forceinline__ u16 f2b(float f) {
  union { float f; u32 u; } v; v.f = f;
  u32 r = (v.u + 0x7FFFu + ((v.u >> 16) & 1u)) >> 16;
  return (u16)r;
}

// ---------- K1: A int32->bf16 0/1 padded to 896x832 ; W2 = [Ws|Wn] bf16 64x128 ----------
__global__ __launch_bounds__(256) void k_prep(const int* __restrict__ adj,
                                              const float* __restrict__ Ws,
                                              const float* __restrict__ Wn,
                                              u16* __restrict__ A,
                                              u16* __restrict__ W2) {
  int t = threadIdx.x;
  if (blockIdx.x < 364) {                     // 364*256*8 = 896*832 elements
    int idx8 = blockIdx.x * 256 + t;
    int i = idx8 / 104, j8 = idx8 - i * 104;  // 104 chunks of 8 per row
    __align__(16) u16 o[8];
    if (i < NNODE && j8 < 98) {               // 98*8 = 784: fully in-range or fully pad
      const int4* ap = (const int4*)(adj + (size_t)i * NNODE + j8 * 8);
      int4 a0 = ap[0], a1 = ap[1];
      o[0] = a0.x ? 0x3F80 : 0; o[1] = a0.y ? 0x3F80 : 0;
      o[2] = a0.z ? 0x3F80 : 0; o[3] = a0.w ? 0x3F80 : 0;
      o[4] = a1.x ? 0x3F80 : 0; o[5] = a1.y ? 0x3F80 : 0;
      o[6] = a1.z ? 0x3F80 : 0; o[7] = a1.w ? 0x3F80 : 0;
    } else {
#pragma unroll
      for (int q = 0; q < 8; ++q) o[q] = 0;
    }
    *(uint4*)(A + (size_t)i * MP + j8 * 8) = *(const uint4*)o;
  } else {                                    // block 364: build W2
    int f = t >> 2, kc = (t & 3) * 32;
    const float* src = (kc < 64) ? (Ws + f * 64 + kc) : (Wn + f * 64 + (kc - 64));
    __align__(16) u16 ob[32];
#pragma unroll
    for (int q = 0; q < 8; ++q) {
      float4 v = ((const float4*)src)[q];
      ob[q * 4 + 0] = f2b(v.x); ob[q * 4 + 1] = f2b(v.y);
      ob[q * 4 + 2] = f2b(v.z); ob[q * 4 + 3] = f2b(v.w);
    }
#pragma unroll
    for (int q = 0; q < 4; ++q)
      *(uint4*)(W2 + f * 128 + kc + q * 8) = ((const uint4*)ob)[q];
  }
}

// ---------- K2: fused e + transpose-scale into Bt[4224][832] ----------
__global__ __launch_bounds__(256) void k_b1t(const float* __restrict__ X,
                                             const float* __restrict__ adst,
                                             u16* __restrict__ Bt) {
  __shared__ float Xs[64][68];
  __shared__ float ad[64];
  __shared__ float es[64];
  int bid = blockIdx.x;
  int b = bid / 13, jt = bid - b * 13;
  int j0 = jt * 64;
  int t = threadIdx.x;
  if (b == 64) {                              // zero pad rows 4160..4223
    int row = 4160 + (t >> 2), c = (t & 3) * 16;
    uint4 z; z.x = 0; z.y = 0; z.z = 0; z.w = 0;
    uint4* p = (uint4*)(Bt + (size_t)row * MP + j0 + c);
    p[0] = z; p[1] = z;
    return;
  }
  int jr = t >> 2, cg = t & 3;
  {
    int j = j0 + jr;
    float4 z4; z4.x = 0.f; z4.y = 0.f; z4.z = 0.f; z4.w = 0.f;
    float4 v0 = z4, v1 = z4, v2 = z4, v3 = z4;
    if (j < NNODE) {
      const float4* xp = (const float4*)(X + ((size_t)b * NNODE + j) * 64 + cg * 16);
      v0 = xp[0]; v1 = xp[1]; v2 = xp[2]; v3 = xp[3];
    }
    float4* d = (float4*)&Xs[jr][cg * 16];
    d[0] = v0; d[1] = v1; d[2] = v2; d[3] = v3;
  }
  if (t < 64) ad[t] = adst[t];
  __syncthreads();
  {
    float dot = 0.f;
#pragma unroll
    for (int q = 0; q < 16; ++q) dot += Xs[jr][cg * 16 + q] * ad[cg * 16 + q];
    dot += __shfl_xor(dot, 1);
    dot += __shfl_xor(dot, 2);
    if (cg == 0) es[jr] = (j0 + jr < NNODE) ? __expf(dot) : 0.f;
  }
  __syncthreads();
  {
    int f = t >> 2, jc = (t & 3) * 16;
    __align__(16) u16 ob[16];
#pragma unroll
    for (int q = 0; q < 16; ++q) ob[q] = f2b(es[jc + q] * Xs[jc + q][f]);
    u16* op = Bt + ((size_t)b * 64 + f) * MP + j0 + jc;
    *(uint4*)op = *(const uint4*)ob;
    *(uint4*)(op + 8) = *(const uint4*)(ob + 8);
  }
  if (t < 64) Bt[(size_t)(4096 + b) * MP + j0 + t] = f2b(es[t]);
}

// ---------- K3: Z[896][4224] bf16 = A @ Bt^T ; 128x128 tile, 4 waves, prefetched ----------
__global__ __launch_bounds__(256) void k_gemm(const u16* __restrict__ A,
                                              const u16* __restrict__ Bt,
                                              u16* __restrict__ Z) {
  __shared__ __align__(16) u16 As[128][LDPG];
  __shared__ __align__(16) u16 Bs[128][LDPG];
  const int t = threadIdx.x;
  const int l = t & 63, w = t >> 6;
  const int wr = w >> 1, wc = w & 1;
  const int g = l >> 4, l15 = l & 15;
  const int n0 = blockIdx.x * 128, i0 = blockIdx.y * 128;
  const int srow = t >> 3, sch = t & 7;       // staging: rows srow+32q, chunk sch

  f32x4 acc[4][4];
#pragma unroll
  for (int a = 0; a < 4; ++a)
#pragma unroll
    for (int bb = 0; bb < 4; ++bb) acc[a][bb] = (f32x4){0.f, 0.f, 0.f, 0.f};

  uint4 ra[4], rb[4];
#pragma unroll
  for (int q = 0; q < 4; ++q) {               // prologue loads kt=0
    int row = q * 32 + srow;
    ra[q] = *(const uint4*)(A + (size_t)(i0 + row) * MP + sch * 8);
    rb[q] = *(const uint4*)(Bt + (size_t)(n0 + row) * MP + sch * 8);
  }
  for (int kt = 0; kt < 13; ++kt) {
#pragma unroll
    for (int q = 0; q < 4; ++q) {
      int row = q * 32 + srow;
      *(uint4*)&As[row][sch * 8] = ra[q];
      *(uint4*)&Bs[row][sch * 8] = rb[q];
    }
    __syncthreads();
    if (kt < 12) {                            // issue-early prefetch (hides under MFMA)
      int k0 = (kt + 1) * 64;
#pragma unroll
      for (int q = 0; q < 4; ++q) {
        int row = q * 32 + srow;
        ra[q] = *(const uint4*)(A + (size_t)(i0 + row) * MP + k0 + sch * 8);
        rb[q] = *(const uint4*)(Bt + (size_t)(n0 + row) * MP + k0 + sch * 8);
      }
    }
#pragma unroll
    for (int kk = 0; kk < 2; ++kk) {
      bf16x8 af[4], bfr[4];
#pragma unroll
      for (int mi = 0; mi < 4; ++mi)
        af[mi] = *(const bf16x8*)&As[wr * 64 + mi * 16 + l15][(kk * 4 + g) * 8];
#pragma unroll
      for (int ni = 0; ni < 4; ++ni)
        bfr[ni] = *(const bf16x8*)&Bs[wc * 64 + ni * 16 + l15][(kk * 4 + g) * 8];
#pragma unroll
      for (int mi = 0; mi < 4; ++mi)
#pragma unroll
        for (int ni = 0; ni < 4; ++ni)
          acc[mi][ni] = __builtin_amdgcn_mfma_f32_16x16x32_bf16(af[mi], bfr[ni], acc[mi][ni], 0, 0, 0);
    }
    __syncthreads();
  }
#pragma unroll
  for (int mi = 0; mi < 4; ++mi) {
    int row = i0 + wr * 64 + mi * 16 + g * 4; // C/D: col=lane&15, row=(lane>>4)*4+reg
#pragma unroll
    for (int ni = 0; ni < 4; ++ni) {
      int col = n0 + wc * 64 + ni * 16 + l15;
#pragma unroll
      for (int j = 0; j < 4; ++j)
        Z[(size_t)(row + j) * NPAD + col] = f2b(acc[mi][ni][j]);
    }
  }
}

// ---------- K4: fused tail: [X | Z/den] @ W2^T + biases ; LN ; ReLU ----------
__global__ __launch_bounds__(256) void k_tail(const float* __restrict__ X,
                                              const u16* __restrict__ Z,
                                              const u16* __restrict__ W2,
                                              const float* __restrict__ bs,
                                              const float* __restrict__ bn,
                                              const float* __restrict__ gam,
                                              const float* __restrict__ bet,
                                              float* __restrict__ out) {
  __shared__ __align__(16) u16 AB[64][LDPT];
  __shared__ __align__(16) u16 WS[64][LDPT];
  __shared__ float comb[64][65];
  __shared__ float dens[64];
  __shared__ float bsL[64], bnL[64], gamL[64], betL[64];
  const int R0 = blockIdx.x * 64;
  const int t = threadIdx.x;
  const int rl = t >> 2, cg = t & 3;
  {
    int R = R0 + rl;
    int bq = R / NNODE, i = R - bq * NNODE;
    if (cg < 2) {                             // X cols cg*32..+31 -> AB[rl][cg*32..]
      const float4* xp = (const float4*)(X + (size_t)R * 64 + cg * 32);
      __align__(16) u16 ob[32];
#pragma unroll
      for (int q = 0; q < 8; ++q) {
        float4 v = xp[q];
        ob[q * 4 + 0] = f2b(v.x); ob[q * 4 + 1] = f2b(v.y);
        ob[q * 4 + 2] = f2b(v.z); ob[q * 4 + 3] = f2b(v.w);
      }
#pragma unroll
      for (int q = 0; q < 4; ++q) *(uint4*)&AB[rl][cg * 32 + q * 8] = ((const uint4*)ob)[q];
    } else {                                  // Z/den cols -> AB[rl][64 + (cg-2)*32..]
      float den = b2f(Z[(size_t)i * NPAD + 4096 + bq]);
      float rden = den > 0.f ? 1.f / den : 0.f;
      if (cg == 2) dens[rl] = den;
      const uint4* zp = (const uint4*)(Z + (size_t)i * NPAD + bq * 64 + (cg - 2) * 32);
#pragma unroll
      for (int q = 0; q < 4; ++q) {
        uint4 v = zp[q];
        u32 ww[4]; ww[0] = v.x; ww[1] = v.y; ww[2] = v.z; ww[3] = v.w;
        __align__(16) u16 ob[8];
#pragma unroll
        for (int p = 0; p < 4; ++p) {
          ob[p * 2]     = f2b(b2f((u16)(ww[p] & 0xFFFFu)) * rden);
          ob[p * 2 + 1] = f2b(b2f((u16)(ww[p] >> 16)) * rden);
        }
        *(uint4*)&AB[rl][64 + (cg - 2) * 32 + q * 8] = *(const uint4*)ob;
      }
    }
    const uint4* wp = (const uint4*)(W2 + rl * 128 + cg * 32);
#pragma unroll
    for (int q = 0; q < 4; ++q) *(uint4*)&WS[rl][cg * 32 + q * 8] = wp[q];
  }
  if (t < 64) { bsL[t] = bs[t]; bnL[t] = bn[t]; gamL[t] = gam[t]; betL[t] = bet[t]; }
  __syncthreads();

  const int w = t >> 6, l = t & 63;
  const int wr = w >> 1, wc = w & 1;
  const int g = l >> 4, l15 = l & 15;
  f32x4 acc[2][2];
#pragma unroll
  for (int a = 0; a < 2; ++a)
#pragma unroll
    for (int bb = 0; bb < 2; ++bb) acc[a][bb] = (f32x4){0.f, 0.f, 0.f, 0.f};
#pragma unroll
  for (int kk = 0; kk < 4; ++kk) {
    bf16x8 af[2], bfr[2];
    af[0]  = *(const bf16x8*)&AB[wr * 32 + l15][(kk * 4 + g) * 8];
    af[1]  = *(const bf16x8*)&AB[wr * 32 + 16 + l15][(kk * 4 + g) * 8];
    bfr[0] = *(const bf16x8*)&WS[wc * 32 + l15][(kk * 4 + g) * 8];
    bfr[1] = *(const bf16x8*)&WS[wc * 32 + 16 + l15][(kk * 4 + g) * 8];
#pragma unroll
    for (int mi = 0; mi < 2; ++mi)
#pragma unroll
      for (int ni = 0; ni < 2; ++ni)
        acc[mi][ni] = __builtin_amdgcn_mfma_f32_16x16x32_bf16(af[mi], bfr[ni], acc[mi][ni], 0, 0, 0);
  }
#pragma unroll
  for (int mi = 0; mi < 2; ++mi) {
    int row = wr * 32 + mi * 16 + g * 4;
#pragma unroll
    for (int ni = 0; ni < 2; ++ni) {
      int col = wc * 32 + ni * 16 + l15;
#pragma unroll
      for (int j = 0; j < 4; ++j) {
        float d = dens[row + j];
        comb[row + j][col] = acc[mi][ni][j] + bsL[col] + (d > 0.f ? bnL[col] : 0.f);
      }
    }
  }
  __syncthreads();
  {
    float v[16];
    float s1 = 0.f, s2 = 0.f;
    int c0 = cg * 16;
#pragma unroll
    for (int q = 0; q < 16; ++q) {
      v[q] = comb[rl][c0 + q];
      s1 += v[q];
      s2 += v[q] * v[q];
    }
    s1 += __shfl_xor(s1, 1); s1 += __shfl_xor(s1, 2);
    s2 += __shfl_xor(s2, 1); s2 += __shfl_xor(s2, 2);
    float mu = s1 * (1.f / 64.f);
    float var = fmaxf(s2 * (1.f / 64.f) - mu * mu, 0.f);
    float inv = rsqrtf(var + 1e-5f);
    float4* op = (float4*)(out + (size_t)(R0 + rl) * 64 + c0);
#pragma unroll
    for (int qq = 0; qq < 4; ++qq) {
      float4 o;
      o.x = fmaxf((v[qq * 4 + 0] - mu) * inv * gamL[c0 + qq * 4 + 0] + betL[c0 + qq * 4 + 0], 0.f);
      o.y = fmaxf((v[qq * 4 + 1] - mu) * inv * gamL[c0 + qq * 4 + 1] + betL[c0 + qq * 4 + 1], 0.f);
      o.z = fmaxf((v[qq * 4 + 2] - mu) * inv * gamL[c0 + qq * 4 + 2] + betL[c0 + qq * 4 + 2], 0.f);
      o.w = fmaxf((v[qq * 4 + 3] - mu) * inv * gamL[c0 + qq * 4 + 3] + betL[c0 + qq * 4 + 3], 0.f);
      op[qq] = o;
    }
  }
}

extern "C" void kernel_launch(void* const* d_in, const int* in_sizes, int n_in,
                              void* d_out, int out_size, void* d_ws, size_t ws_size,
                              hipStream_t stream) {
  const float* X     = (const float*)d_in[0];
  const int*   adj   = (const int*)d_in[1];
  const float* Wself = (const float*)d_in[2];
  const float* bself = (const float*)d_in[3];
  const float* Wnb   = (const float*)d_in[4];
  const float* bnb   = (const float*)d_in[5];
  // d_in[6] = a_src : cancels in softmax -> unused
  const float* adst  = (const float*)d_in[7];
  // d_in[8] = b_att : cancels in softmax -> unused
  const float* gam   = (const float*)d_in[9];
  const float* bet   = (const float*)d_in[10];
  float* out = (float*)d_out;
  char* ws = (char*)d_ws;

  u16* Apad = (u16*)(ws);                    // 896*832  bf16 = 1,490,944 B
  u16* W2g  = (u16*)(ws + 1490944);          // 64*128   bf16 =    16,384 B
  u16* Bt   = (u16*)(ws + 1507328);          // 4224*832 bf16 = 7,028,736 B
  u16* Zb   = (u16*)(ws + 8536064);          // 896*4224 bf16 = 7,569,408 B (end 16,105,472)

  k_prep<<<dim3(365),    dim3(256), 0, stream>>>(adj, Wself, Wnb, Apad, W2g);
  k_b1t <<<dim3(845),    dim3(256), 0, stream>>>(X, adst, Bt);
  k_gemm<<<dim3(33, 7),  dim3(256), 0, stream>>>(Apad, Bt, Zb);
  k_tail<<<dim3(784),    dim3(256), 0, stream>>>(X, Zb, W2g, bself, bnb, gam, bet, out);
}

// Round 5
// 46.325 us; speedup vs baseline: 1.5135x; 1.5135x over previous
//
#include <hip/hip_runtime.h>

// GraphConvLayer on MI355X (gfx950). f32 I/O, bf16 inside MFMA.
// softmax_j(src_i+dst_j+b) over neighbors == e_j/sum(e)  (src_i, b cancel).
//   Bt[n][k]: n=b*64+f -> bf16(e_bj * X[b,j,f]) (k=j); n=4096+b -> bf16(e_bj)
//   Z = A_pad(896x832) @ Bt^T   -> Z[i][b*64+f] = agg_unnorm, Z[i][4096+b] = denom
//   out = relu(LN( [X | Z/den] @ [Ws|Wn]^T + bs + bn*(den>0) ))
// k_gemm: 128x128 tile, 8 waves, global_load_lds + double-buffer LDS,
//         1 barrier/K-step (T3 2-phase), XOR chunk swizzle both sides (T2/G21).

typedef unsigned short u16;
typedef unsigned int u32;
typedef short bf16x8 __attribute__((ext_vector_type(8)));
typedef float f32x4 __attribute__((ext_vector_type(4)));

#define NNODE 784
#define MP 832      // K (padded node count)
#define MT 896      // padded rows of A / Z (7 x 128)
#define NPAD 4224   // padded cols of Z (33 x 128): 4096 feats + 64 denom + 64 pad
#define LDPT 136    // tail LDS pitch (u16)
#define GLDS 8192   // u16 per 128x64 tile matrix

__device__ __forceinline__ float b2f(u16 h) {
  union { u32 u; float f; } v; v.u = ((u32)h) << 16; return v.f;
}
__device__ __forceinline__ u16 f2b(float f) {
  union { float f; u32 u; } v; v.f = f;
  u32 r = (v.u + 0x7FFFu + ((v.u >> 16) & 1u)) >> 16;
  return (u16)r;
}
__device__ __forceinline__ void gload16(const u16* g, u16* l) {
  __builtin_amdgcn_global_load_lds((const __attribute__((address_space(1))) u32*)g,
                                   (__attribute__((address_space(3))) u32*)l, 16, 0, 0);
}

// ---------- K1: A int32->bf16 0/1 padded to 896x832 ; W2 = [Ws|Wn] bf16 64x128 ----------
__global__ __launch_bounds__(256) void k_prep(const int* __restrict__ adj,
                                              const float* __restrict__ Ws,
                                              const float* __restrict__ Wn,
                                              u16* __restrict__ A,
                                              u16* __restrict__ W2) {
  int t = threadIdx.x;
  if (blockIdx.x < 364) {                     // 364*256*8 = 896*832 elements
    int idx8 = blockIdx.x * 256 + t;
    int i = idx8 / 104, j8 = idx8 - i * 104;
    __align__(16) u16 o[8];
    if (i < NNODE && j8 < 98) {               // 98*8 = 784
      const int4* ap = (const int4*)(adj + (size_t)i * NNODE + j8 * 8);
      int4 a0 = ap[0], a1 = ap[1];
      o[0] = a0.x ? 0x3F80 : 0; o[1] = a0.y ? 0x3F80 : 0;
      o[2] = a0.z ? 0x3F80 : 0; o[3] = a0.w ? 0x3F80 : 0;
      o[4] = a1.x ? 0x3F80 : 0; o[5] = a1.y ? 0x3F80 : 0;
      o[6] = a1.z ? 0x3F80 : 0; o[7] = a1.w ? 0x3F80 : 0;
    } else {
#pragma unroll
      for (int q = 0; q < 8; ++q) o[q] = 0;
    }
    *(uint4*)(A + (size_t)i * MP + j8 * 8) = *(const uint4*)o;
  } else {                                    // block 364: build W2
    int f = t >> 2, kc = (t & 3) * 32;
    const float* src = (kc < 64) ? (Ws + f * 64 + kc) : (Wn + f * 64 + (kc - 64));
    __align__(16) u16 ob[32];
#pragma unroll
    for (int q = 0; q < 8; ++q) {
      float4 v = ((const float4*)src)[q];
      ob[q * 4 + 0] = f2b(v.x); ob[q * 4 + 1] = f2b(v.y);
      ob[q * 4 + 2] = f2b(v.z); ob[q * 4 + 3] = f2b(v.w);
    }
#pragma unroll
    for (int q = 0; q < 4; ++q)
      *(uint4*)(W2 + f * 128 + kc + q * 8) = ((const uint4*)ob)[q];
  }
}

// ---------- K2: fused e + transpose-scale into Bt[4224][832] ----------
__global__ __launch_bounds__(256) void k_b1t(const float* __restrict__ X,
                                             const float* __restrict__ adst,
                                             u16* __restrict__ Bt) {
  __shared__ float Xs[64][68];
  __shared__ float ad[64];
  __shared__ float es[64];
  int bid = blockIdx.x;
  int b = bid / 13, jt = bid - b * 13;
  int j0 = jt * 64;
  int t = threadIdx.x;
  if (b == 64) {                              // zero pad rows 4160..4223
    int row = 4160 + (t >> 2), c = (t & 3) * 16;
    uint4 z; z.x = 0; z.y = 0; z.z = 0; z.w = 0;
    uint4* p = (uint4*)(Bt + (size_t)row * MP + j0 + c);
    p[0] = z; p[1] = z;
    return;
  }
  int jr = t >> 2, cg = t & 3;
  {
    int j = j0 + jr;
    float4 z4; z4.x = 0.f; z4.y = 0.f; z4.z = 0.f; z4.w = 0.f;
    float4 v0 = z4, v1 = z4, v2 = z4, v3 = z4;
    if (j < NNODE) {
      const float4* xp = (const float4*)(X + ((size_t)b * NNODE + j) * 64 + cg * 16);
      v0 = xp[0]; v1 = xp[1]; v2 = xp[2]; v3 = xp[3];
    }
    float4* d = (float4*)&Xs[jr][cg * 16];
    d[0] = v0; d[1] = v1; d[2] = v2; d[3] = v3;
  }
  if (t < 64) ad[t] = adst[t];
  __syncthreads();
  {
    float dot = 0.f;
#pragma unroll
    for (int q = 0; q < 16; ++q) dot += Xs[jr][cg * 16 + q] * ad[cg * 16 + q];
    dot += __shfl_xor(dot, 1);
    dot += __shfl_xor(dot, 2);
    if (cg == 0) es[jr] = (j0 + jr < NNODE) ? __expf(dot) : 0.f;
  }
  __syncthreads();
  {
    int f = t >> 2, jc = (t & 3) * 16;
    __align__(16) u16 ob[16];
#pragma unroll
    for (int q = 0; q < 16; ++q) ob[q] = f2b(es[jc + q] * Xs[jc + q][f]);
    u16* op = Bt + ((size_t)b * 64 + f) * MP + j0 + jc;
    *(uint4*)op = *(const uint4*)ob;
    *(uint4*)(op + 8) = *(const uint4*)(ob + 8);
  }
  if (t < 64) Bt[(size_t)(4096 + b) * MP + j0 + t] = f2b(es[t]);
}

// ---------- K3: Z[896][4224] bf16 = A @ Bt^T ; async dbuf, 1 barrier/kt ----------
__global__ __launch_bounds__(512) void k_gemm(const u16* __restrict__ A,
                                              const u16* __restrict__ Bt,
                                              u16* __restrict__ Z) {
  __shared__ __align__(16) u16 lds[4 * GLDS];   // [buf0 A,B][buf1 A,B] = 64 KB
  const int t = threadIdx.x;
  const int l = t & 63, w = t >> 6;             // 8 waves
  const int wr = w >> 2, wc = w & 3;            // wave -> 64x32 out sub-tile
  const int g = l >> 4, l15 = l & 15;
  const int n0 = blockIdx.x * 128, i0 = blockIdx.y * 128;
  const int lr = l >> 3, lc = l & 7;
  const int ssrc = (lc ^ lr) * 8;               // pre-swizzled source col (u16)

  f32x4 acc[4][2];
#pragma unroll
  for (int mi = 0; mi < 4; ++mi)
#pragma unroll
    for (int ni = 0; ni < 2; ++ni) acc[mi][ni] = (f32x4){0.f, 0.f, 0.f, 0.f};

  // stage K-tile kt into buffer buf: 16 x 1KB wave-chunks per matrix
#define STAGE(kt_, buf_)                                                        \
  {                                                                             \
    int k0_ = (kt_) * 64;                                                       \
    u16* dA_ = lds + (buf_) * 2 * GLDS;                                         \
    u16* dB_ = dA_ + GLDS;                                                      \
    _Pragma("unroll")                                                           \
    for (int h_ = 0; h_ < 2; ++h_) {                                            \
      int m_ = w + h_ * 8;                                                      \
      int row_ = m_ * 8 + lr;                                                   \
      gload16(A + (size_t)(i0 + row_) * MP + k0_ + ssrc, dA_ + m_ * 512);       \
      gload16(Bt + (size_t)(n0 + row_) * MP + k0_ + ssrc, dB_ + m_ * 512);      \
    }                                                                           \
  }

  STAGE(0, 0);
  __syncthreads();                              // implicit vmcnt(0): buf0 ready

  for (int kt = 0; kt < 13; ++kt) {
    int buf = kt & 1;
    if (kt < 12) STAGE(kt + 1, buf ^ 1);        // async; lands during MFMA phase
    const u16* As = lds + buf * 2 * GLDS;
    const u16* Bs = As + GLDS;
#pragma unroll
    for (int kk = 0; kk < 2; ++kk) {
      int q = kk * 4 + g;
      bf16x8 af[4], bfr[2];
#pragma unroll
      for (int mi = 0; mi < 4; ++mi) {
        int ra = wr * 64 + mi * 16 + l15;
        af[mi] = *(const bf16x8*)(As + ra * 64 + (q ^ (ra & 7)) * 8);
      }
#pragma unroll
      for (int ni = 0; ni < 2; ++ni) {
        int rb = wc * 32 + ni * 16 + l15;
        bfr[ni] = *(const bf16x8*)(Bs + rb * 64 + (q ^ (rb & 7)) * 8);
      }
#pragma unroll
      for (int mi = 0; mi < 4; ++mi)
#pragma unroll
        for (int ni = 0; ni < 2; ++ni)
          acc[mi][ni] = __builtin_amdgcn_mfma_f32_16x16x32_bf16(af[mi], bfr[ni], acc[mi][ni], 0, 0, 0);
    }
    __syncthreads();                            // drains this wave's gloads too
  }
#pragma unroll
  for (int mi = 0; mi < 4; ++mi) {
    int row = i0 + wr * 64 + mi * 16 + g * 4;   // C/D: col=lane&15, row=(lane>>4)*4+reg
#pragma unroll
    for (int ni = 0; ni < 2; ++ni) {
      int col = n0 + wc * 32 + ni * 16 + l15;
#pragma unroll
      for (int j = 0; j < 4; ++j)
        Z[(size_t)(row + j) * NPAD + col] = f2b(acc[mi][ni][j]);
    }
  }
#undef STAGE
}

// ---------- K4: fused tail: [X | Z/den] @ W2^T + biases ; LN ; ReLU ----------
__global__ __launch_bounds__(256) void k_tail(const float* __restrict__ X,
                                              const u16* __restrict__ Z,
                                              const u16* __restrict__ W2,
                                              const float* __restrict__ bs,
                                              const float* __restrict__ bn,
                                              const float* __restrict__ gam,
                                              const float* __restrict__ bet,
                                              float* __restrict__ out) {
  __shared__ __align__(16) u16 AB[64][LDPT];
  __shared__ __align__(16) u16 WS[64][LDPT];
  __shared__ float comb[64][65];
  __shared__ float dens[64];
  __shared__ float bsL[64], bnL[64], gamL[64], betL[64];
  const int R0 = blockIdx.x * 64;
  const int t = threadIdx.x;
  const int rl = t >> 2, cg = t & 3;
  {
    int R = R0 + rl;
    int bq = R / NNODE, i = R - bq * NNODE;
    if (cg < 2) {
      const float4* xp = (const float4*)(X + (size_t)R * 64 + cg * 32);
      __align__(16) u16 ob[32];
#pragma unroll
      for (int q = 0; q < 8; ++q) {
        float4 v = xp[q];
        ob[q * 4 + 0] = f2b(v.x); ob[q * 4 + 1] = f2b(v.y);
        ob[q * 4 + 2] = f2b(v.z); ob[q * 4 + 3] = f2b(v.w);
      }
#pragma unroll
      for (int q = 0; q < 4; ++q) *(uint4*)&AB[rl][cg * 32 + q * 8] = ((const uint4*)ob)[q];
    } else {
      float den = b2f(Z[(size_t)i * NPAD + 4096 + bq]);
      float rden = den > 0.f ? 1.f / den : 0.f;
      if (cg == 2) dens[rl] = den;
      const uint4* zp = (const uint4*)(Z + (size_t)i * NPAD + bq * 64 + (cg - 2) * 32);
#pragma unroll
      for (int q = 0; q < 4; ++q) {
        uint4 v = zp[q];
        u32 ww[4]; ww[0] = v.x; ww[1] = v.y; ww[2] = v.z; ww[3] = v.w;
        __align__(16) u16 ob[8];
#pragma unroll
        for (int p = 0; p < 4; ++p) {
          ob[p * 2]     = f2b(b2f((u16)(ww[p] & 0xFFFFu)) * rden);
          ob[p * 2 + 1] = f2b(b2f((u16)(ww[p] >> 16)) * rden);
        }
        *(uint4*)&AB[rl][64 + (cg - 2) * 32 + q * 8] = *(const uint4*)ob;
      }
    }
    const uint4* wp = (const uint4*)(W2 + rl * 128 + cg * 32);
#pragma unroll
    for (int q = 0; q < 4; ++q) *(uint4*)&WS[rl][cg * 32 + q * 8] = wp[q];
  }
  if (t < 64) { bsL[t] = bs[t]; bnL[t] = bn[t]; gamL[t] = gam[t]; betL[t] = bet[t]; }
  __syncthreads();

  const int w = t >> 6, l = t & 63;
  const int wr = w >> 1, wc = w & 1;
  const int g = l >> 4, l15 = l & 15;
  f32x4 acc[2][2];
#pragma unroll
  for (int a = 0; a < 2; ++a)
#pragma unroll
    for (int bb = 0; bb < 2; ++bb) acc[a][bb] = (f32x4){0.f, 0.f, 0.f, 0.f};
#pragma unroll
  for (int kk = 0; kk < 4; ++kk) {
    bf16x8 af[2], bfr[2];
    af[0]  = *(const bf16x8*)&AB[wr * 32 + l15][(kk * 4 + g) * 8];
    af[1]  = *(const bf16x8*)&AB[wr * 32 + 16 + l15][(kk * 4 + g) * 8];
    bfr[0] = *(const bf16x8*)&WS[wc * 32 + l15][(kk * 4 + g) * 8];
    bfr[1] = *(const bf16x8*)&WS[wc * 32 + 16 + l15][(kk * 4 + g) * 8];
#pragma unroll
    for (int mi = 0; mi < 2; ++mi)
#pragma unroll
      for (int ni = 0; ni < 2; ++ni)
        acc[mi][ni] = __builtin_amdgcn_mfma_f32_16x16x32_bf16(af[mi], bfr[ni], acc[mi][ni], 0, 0, 0);
  }
#pragma unroll
  for (int mi = 0; mi < 2; ++mi) {
    int row = wr * 32 + mi * 16 + g * 4;
#pragma unroll
    for (int ni = 0; ni < 2; ++ni) {
      int col = wc * 32 + ni * 16 + l15;
#pragma unroll
      for (int j = 0; j < 4; ++j) {
        float d = dens[row + j];
        comb[row + j][col] = acc[mi][ni][j] + bsL[col] + (d > 0.f ? bnL[col] : 0.f);
      }
    }
  }
  __syncthreads();
  {
    float v[16];
    float s1 = 0.f, s2 = 0.f;
    int c0 = cg * 16;
#pragma unroll
    for (int q = 0; q < 16; ++q) {
      v[q] = comb[rl][c0 + q];
      s1 += v[q];
      s2 += v[q] * v[q];
    }
    s1 += __shfl_xor(s1, 1); s1 += __shfl_xor(s1, 2);
    s2 += __shfl_xor(s2, 1); s2 += __shfl_xor(s2, 2);
    float mu = s1 * (1.f / 64.f);
    float var = fmaxf(s2 * (1.f / 64.f) - mu * mu, 0.f);
    float inv = rsqrtf(var + 1e-5f);
    float4* op = (float4*)(out + (size_t)(R0 + rl) * 64 + c0);
#pragma unroll
    for (int qq = 0; qq < 4; ++qq) {
      float4 o;
      o.x = fmaxf((v[qq * 4 + 0] - mu) * inv * gamL[c0 + qq * 4 + 0] + betL[c0 + qq * 4 + 0], 0.f);
      o.y = fmaxf((v[qq * 4 + 1] - mu) * inv * gamL[c0 + qq * 4 + 1] + betL[c0 + qq * 4 + 1], 0.f);
      o.z = fmaxf((v[qq * 4 + 2] - mu) * inv * gamL[c0 + qq * 4 + 2] + betL[c0 + qq * 4 + 2], 0.f);
      o.w = fmaxf((v[qq * 4 + 3] - mu) * inv * gamL[c0 + qq * 4 + 3] + betL[c0 + qq * 4 + 3], 0.f);
      op[qq] = o;
    }
  }
}

extern "C" void kernel_launch(void* const* d_in, const int* in_sizes, int n_in,
                              void* d_out, int out_size, void* d_ws, size_t ws_size,
                              hipStream_t stream) {
  const float* X     = (const float*)d_in[0];
  const int*   adj   = (const int*)d_in[1];
  const float* Wself = (const float*)d_in[2];
  const float* bself = (const float*)d_in[3];
  const float* Wnb   = (const float*)d_in[4];
  const float* bnb   = (const float*)d_in[5];
  // d_in[6] = a_src : cancels in softmax -> unused
  const float* adst  = (const float*)d_in[7];
  // d_in[8] = b_att : cancels in softmax -> unused
  const float* gam   = (const float*)d_in[9];
  const float* bet   = (const float*)d_in[10];
  float* out = (float*)d_out;
  char* ws = (char*)d_ws;

  u16* Apad = (u16*)(ws);                    // 896*832  bf16 = 1,490,944 B
  u16* W2g  = (u16*)(ws + 1490944);          // 64*128   bf16 =    16,384 B
  u16* Bt   = (u16*)(ws + 1507328);          // 4224*832 bf16 = 7,028,736 B
  u16* Zb   = (u16*)(ws + 8536064);          // 896*4224 bf16 = 7,569,408 B (end 16,105,472)

  k_prep<<<dim3(365),    dim3(256), 0, stream>>>(adj, Wself, Wnb, Apad, W2g);
  k_b1t <<<dim3(845),    dim3(256), 0, stream>>>(X, adst, Bt);
  k_gemm<<<dim3(33, 7),  dim3(512), 0, stream>>>(Apad, Bt, Zb);
  k_tail<<<dim3(784),    dim3(256), 0, stream>>>(X, Zb, W2g, bself, bnb, gam, bet, out);
}

// Round 6
// 41.980 us; speedup vs baseline: 1.6702x; 1.1035x over previous
//
#include <hip/hip_runtime.h>

// GraphConvLayer on MI355X (gfx950). f32 I/O, bf16 inside MFMA.
// softmax_j(src_i+dst_j+b) over neighbors == e_j/sum(e)  (src_i, b cancel).
//   Bt[n][k]: n=b*64+f -> bf16(e_bj * X[b,j,f]) (k=j); n=4096+b -> bf16(e_bj)
//   Z = A_pad(896x832) @ Bt^T   -> Z[i][b*64+f] = agg_unnorm, Z[i][4096+b] = denom
//   out = relu(LN( [X | Z/den] @ [Ws|Wn]^T + bs + bn*(den>0) ))
// k_gemm: 64x128 tile (462 blocks ~2/CU for latency hiding), 8 waves,
//         global_load_lds dbuf, 1 barrier/K-step, XOR chunk swizzle both sides,
//         bijective XCD-chunked block swizzle (n-major).

typedef unsigned short u16;
typedef unsigned int u32;
typedef short bf16x8 __attribute__((ext_vector_type(8)));
typedef float f32x4 __attribute__((ext_vector_type(4)));

#define NNODE 784
#define MP 832      // K (padded node count)
#define MT 896      // padded rows of A / Z (14 x 64)
#define NPAD 4224   // padded cols of Z (33 x 128): 4096 feats + 64 denom + 64 pad
#define LDPT 136    // tail LDS pitch (u16)

__device__ __forceinline__ float b2f(u16 h) {
  union { u32 u; float f; } v; v.u = ((u32)h) << 16; return v.f;
}
__device__ __forceinline__ u16 f2b(float f) {
  union { float f; u32 u; } v; v.f = f;
  u32 r = (v.u + 0x7FFFu + ((v.u >> 16) & 1u)) >> 16;
  return (u16)r;
}
__device__ __forceinline__ void gload16(const u16* g, u16* l) {
  __builtin_amdgcn_global_load_lds((const __attribute__((address_space(1))) u32*)g,
                                   (__attribute__((address_space(3))) u32*)l, 16, 0, 0);
}

// ---------- K1: A int32->bf16 0/1 padded to 896x832 ; W2 = [Ws|Wn] bf16 64x128 ----------
__global__ __launch_bounds__(256) void k_prep(const int* __restrict__ adj,
                                              const float* __restrict__ Ws,
                                              const float* __restrict__ Wn,
                                              u16* __restrict__ A,
                                              u16* __restrict__ W2) {
  int t = threadIdx.x;
  if (blockIdx.x < 364) {                     // 364*256*8 = 896*832 elements
    int idx8 = blockIdx.x * 256 + t;
    int i = idx8 / 104, j8 = idx8 - i * 104;
    __align__(16) u16 o[8];
    if (i < NNODE && j8 < 98) {               // 98*8 = 784
      const int4* ap = (const int4*)(adj + (size_t)i * NNODE + j8 * 8);
      int4 a0 = ap[0], a1 = ap[1];
      o[0] = a0.x ? 0x3F80 : 0; o[1] = a0.y ? 0x3F80 : 0;
      o[2] = a0.z ? 0x3F80 : 0; o[3] = a0.w ? 0x3F80 : 0;
      o[4] = a1.x ? 0x3F80 : 0; o[5] = a1.y ? 0x3F80 : 0;
      o[6] = a1.z ? 0x3F80 : 0; o[7] = a1.w ? 0x3F80 : 0;
    } else {
#pragma unroll
      for (int q = 0; q < 8; ++q) o[q] = 0;
    }
    *(uint4*)(A + (size_t)i * MP + j8 * 8) = *(const uint4*)o;
  } else {                                    // block 364: build W2
    int f = t >> 2, kc = (t & 3) * 32;
    const float* src = (kc < 64) ? (Ws + f * 64 + kc) : (Wn + f * 64 + (kc - 64));
    __align__(16) u16 ob[32];
#pragma unroll
    for (int q = 0; q < 8; ++q) {
      float4 v = ((const float4*)src)[q];
      ob[q * 4 + 0] = f2b(v.x); ob[q * 4 + 1] = f2b(v.y);
      ob[q * 4 + 2] = f2b(v.z); ob[q * 4 + 3] = f2b(v.w);
    }
#pragma unroll
    for (int q = 0; q < 4; ++q)
      *(uint4*)(W2 + f * 128 + kc + q * 8) = ((const uint4*)ob)[q];
  }
}

// ---------- K2: fused e + transpose-scale into Bt[4224][832] ----------
__global__ __launch_bounds__(256) void k_b1t(const float* __restrict__ X,
                                             const float* __restrict__ adst,
                                             u16* __restrict__ Bt) {
  __shared__ float Xs[64][68];
  __shared__ float ad[64];
  __shared__ float es[64];
  int bid = blockIdx.x;
  int b = bid / 13, jt = bid - b * 13;
  int j0 = jt * 64;
  int t = threadIdx.x;
  if (b == 64) {                              // zero pad rows 4160..4223
    int row = 4160 + (t >> 2), c = (t & 3) * 16;
    uint4 z; z.x = 0; z.y = 0; z.z = 0; z.w = 0;
    uint4* p = (uint4*)(Bt + (size_t)row * MP + j0 + c);
    p[0] = z; p[1] = z;
    return;
  }
  int jr = t >> 2, cg = t & 3;
  {
    int j = j0 + jr;
    float4 z4; z4.x = 0.f; z4.y = 0.f; z4.z = 0.f; z4.w = 0.f;
    float4 v0 = z4, v1 = z4, v2 = z4, v3 = z4;
    if (j < NNODE) {
      const float4* xp = (const float4*)(X + ((size_t)b * NNODE + j) * 64 + cg * 16);
      v0 = xp[0]; v1 = xp[1]; v2 = xp[2]; v3 = xp[3];
    }
    float4* d = (float4*)&Xs[jr][cg * 16];
    d[0] = v0; d[1] = v1; d[2] = v2; d[3] = v3;
  }
  if (t < 64) ad[t] = adst[t];
  __syncthreads();
  {
    float dot = 0.f;
#pragma unroll
    for (int q = 0; q < 16; ++q) dot += Xs[jr][cg * 16 + q] * ad[cg * 16 + q];
    dot += __shfl_xor(dot, 1);
    dot += __shfl_xor(dot, 2);
    if (cg == 0) es[jr] = (j0 + jr < NNODE) ? __expf(dot) : 0.f;
  }
  __syncthreads();
  {
    int f = t >> 2, jc = (t & 3) * 16;
    __align__(16) u16 ob[16];
#pragma unroll
    for (int q = 0; q < 16; ++q) ob[q] = f2b(es[jc + q] * Xs[jc + q][f]);
    u16* op = Bt + ((size_t)b * 64 + f) * MP + j0 + jc;
    *(uint4*)op = *(const uint4*)ob;
    *(uint4*)(op + 8) = *(const uint4*)(ob + 8);
  }
  if (t < 64) Bt[(size_t)(4096 + b) * MP + j0 + t] = f2b(es[t]);
}

// ---------- K3: Z[896][4224] bf16 = A @ Bt^T ; 64x128 tile, async dbuf ----------
__global__ __launch_bounds__(512) void k_gemm(const u16* __restrict__ A,
                                              const u16* __restrict__ Bt,
                                              u16* __restrict__ Z) {
  __shared__ __align__(16) u16 lds[2 * 12288];  // per buf: [A 64x64][B 128x64] = 24 KB
  const int t = threadIdx.x;
  const int l = t & 63, w = t >> 6;             // 8 waves
  const int wr = w >> 2, wc = w & 3;            // wave -> 32x32 out sub-tile
  const int g = l >> 4, l15 = l & 15;
  const int lr = l >> 3, lc = l & 7;
  const int ssrc = (lc ^ lr) * 8;               // pre-swizzled source col (u16)

  // bijective XCD-chunked swizzle (nwg=462, q=57, r=6), n-major decomposition
  int orig = blockIdx.x;
  int xcd = orig & 7, idx = orig >> 3;
  int wg = (xcd < 6) ? (xcd * 58 + idx) : (6 * 58 + (xcd - 6) * 57 + idx);
  const int n0 = (wg / 14) * 128, i0 = (wg - (wg / 14) * 14) * 64;

  f32x4 acc[2][2];
#pragma unroll
  for (int mi = 0; mi < 2; ++mi)
#pragma unroll
    for (int ni = 0; ni < 2; ++ni) acc[mi][ni] = (f32x4){0.f, 0.f, 0.f, 0.f};

#define STAGE(kt_, buf_)                                                         \
  {                                                                              \
    int k0_ = (kt_) * 64;                                                        \
    u16* dA_ = lds + (buf_) * 12288;                                             \
    u16* dB_ = dA_ + 4096;                                                       \
    gload16(A + (size_t)(i0 + w * 8 + lr) * MP + k0_ + ssrc, dA_ + w * 512);     \
    gload16(Bt + (size_t)(n0 + w * 8 + lr) * MP + k0_ + ssrc, dB_ + w * 512);    \
    gload16(Bt + (size_t)(n0 + 64 + w * 8 + lr) * MP + k0_ + ssrc,               \
            dB_ + 4096 + w * 512);                                               \
  }

  STAGE(0, 0);
  __syncthreads();                              // implicit vmcnt(0): buf0 ready

  for (int kt = 0; kt < 13; ++kt) {
    int buf = kt & 1;
    if (kt < 12) STAGE(kt + 1, buf ^ 1);        // lands during MFMA phase
    const u16* As = lds + buf * 12288;
    const u16* Bs = As + 4096;
#pragma unroll
    for (int kk = 0; kk < 2; ++kk) {
      int q = kk * 4 + g;
      bf16x8 af[2], bfr[2];
#pragma unroll
      for (int mi = 0; mi < 2; ++mi) {
        int ra = wr * 32 + mi * 16 + l15;
        af[mi] = *(const bf16x8*)(As + ra * 64 + (q ^ (ra & 7)) * 8);
      }
#pragma unroll
      for (int ni = 0; ni < 2; ++ni) {
        int rb = wc * 32 + ni * 16 + l15;
        bfr[ni] = *(const bf16x8*)(Bs + rb * 64 + (q ^ (rb & 7)) * 8);
      }
#pragma unroll
      for (int mi = 0; mi < 2; ++mi)
#pragma unroll
        for (int ni = 0; ni < 2; ++ni)
          acc[mi][ni] = __builtin_amdgcn_mfma_f32_16x16x32_bf16(af[mi], bfr[ni], acc[mi][ni], 0, 0, 0);
    }
    __syncthreads();
  }
#pragma unroll
  for (int mi = 0; mi < 2; ++mi) {
    int row = i0 + wr * 32 + mi * 16 + g * 4;   // C/D: col=lane&15, row=(lane>>4)*4+reg
#pragma unroll
    for (int ni = 0; ni < 2; ++ni) {
      int col = n0 + wc * 32 + ni * 16 + l15;
#pragma unroll
      for (int j = 0; j < 4; ++j)
        Z[(size_t)(row + j) * NPAD + col] = f2b(acc[mi][ni][j]);
    }
  }
#undef STAGE
}

// ---------- K4: fused tail: [X | Z/den] @ W2^T + biases ; LN ; ReLU ----------
__global__ __launch_bounds__(256) void k_tail(const float* __restrict__ X,
                                              const u16* __restrict__ Z,
                                              const u16* __restrict__ W2,
                                              const float* __restrict__ bs,
                                              const float* __restrict__ bn,
                                              const float* __restrict__ gam,
                                              const float* __restrict__ bet,
                                              float* __restrict__ out) {
  __shared__ __align__(16) u16 AB[64][LDPT];
  __shared__ __align__(16) u16 WS[64][LDPT];
  __shared__ float comb[64][65];
  __shared__ float dens[64];
  __shared__ float bsL[64], bnL[64], gamL[64], betL[64];
  const int R0 = blockIdx.x * 64;
  const int t = threadIdx.x;
  const int rl = t >> 2, cg = t & 3;
  {
    int R = R0 + rl;
    int bq = R / NNODE, i = R - bq * NNODE;
    if (cg < 2) {
      const float4* xp = (const float4*)(X + (size_t)R * 64 + cg * 32);
      __align__(16) u16 ob[32];
#pragma unroll
      for (int q = 0; q < 8; ++q) {
        float4 v = xp[q];
        ob[q * 4 + 0] = f2b(v.x); ob[q * 4 + 1] = f2b(v.y);
        ob[q * 4 + 2] = f2b(v.z); ob[q * 4 + 3] = f2b(v.w);
      }
#pragma unroll
      for (int q = 0; q < 4; ++q) *(uint4*)&AB[rl][cg * 32 + q * 8] = ((const uint4*)ob)[q];
    } else {
      float den = b2f(Z[(size_t)i * NPAD + 4096 + bq]);
      float rden = den > 0.f ? 1.f / den : 0.f;
      if (cg == 2) dens[rl] = den;
      const uint4* zp = (const uint4*)(Z + (size_t)i * NPAD + bq * 64 + (cg - 2) * 32);
#pragma unroll
      for (int q = 0; q < 4; ++q) {
        uint4 v = zp[q];
        u32 ww[4]; ww[0] = v.x; ww[1] = v.y; ww[2] = v.z; ww[3] = v.w;
        __align__(16) u16 ob[8];
#pragma unroll
        for (int p = 0; p < 4; ++p) {
          ob[p * 2]     = f2b(b2f((u16)(ww[p] & 0xFFFFu)) * rden);
          ob[p * 2 + 1] = f2b(b2f((u16)(ww[p] >> 16)) * rden);
        }
        *(uint4*)&AB[rl][64 + (cg - 2) * 32 + q * 8] = *(const uint4*)ob;
      }
    }
    const uint4* wp = (const uint4*)(W2 + rl * 128 + cg * 32);
#pragma unroll
    for (int q = 0; q < 4; ++q) *(uint4*)&WS[rl][cg * 32 + q * 8] = wp[q];
  }
  if (t < 64) { bsL[t] = bs[t]; bnL[t] = bn[t]; gamL[t] = gam[t]; betL[t] = bet[t]; }
  __syncthreads();

  const int w = t >> 6, l = t & 63;
  const int wr = w >> 1, wc = w & 1;
  const int g = l >> 4, l15 = l & 15;
  f32x4 acc[2][2];
#pragma unroll
  for (int a = 0; a < 2; ++a)
#pragma unroll
    for (int bb = 0; bb < 2; ++bb) acc[a][bb] = (f32x4){0.f, 0.f, 0.f, 0.f};
#pragma unroll
  for (int kk = 0; kk < 4; ++kk) {
    bf16x8 af[2], bfr[2];
    af[0]  = *(const bf16x8*)&AB[wr * 32 + l15][(kk * 4 + g) * 8];
    af[1]  = *(const bf16x8*)&AB[wr * 32 + 16 + l15][(kk * 4 + g) * 8];
    bfr[0] = *(const bf16x8*)&WS[wc * 32 + l15][(kk * 4 + g) * 8];
    bfr[1] = *(const bf16x8*)&WS[wc * 32 + 16 + l15][(kk * 4 + g) * 8];
#pragma unroll
    for (int mi = 0; mi < 2; ++mi)
#pragma unroll
      for (int ni = 0; ni < 2; ++ni)
        acc[mi][ni] = __builtin_amdgcn_mfma_f32_16x16x32_bf16(af[mi], bfr[ni], acc[mi][ni], 0, 0, 0);
  }
#pragma unroll
  for (int mi = 0; mi < 2; ++mi) {
    int row = wr * 32 + mi * 16 + g * 4;
#pragma unroll
    for (int ni = 0; ni < 2; ++ni) {
      int col = wc * 32 + ni * 16 + l15;
#pragma unroll
      for (int j = 0; j < 4; ++j) {
        float d = dens[row + j];
        comb[row + j][col] = acc[mi][ni][j] + bsL[col] + (d > 0.f ? bnL[col] : 0.f);
      }
    }
  }
  __syncthreads();
  {
    float v[16];
    float s1 = 0.f, s2 = 0.f;
    int c0 = cg * 16;
#pragma unroll
    for (int q = 0; q < 16; ++q) {
      v[q] = comb[rl][c0 + q];
      s1 += v[q];
      s2 += v[q] * v[q];
    }
    s1 += __shfl_xor(s1, 1); s1 += __shfl_xor(s1, 2);
    s2 += __shfl_xor(s2, 1); s2 += __shfl_xor(s2, 2);
    float mu = s1 * (1.f / 64.f);
    float var = fmaxf(s2 * (1.f / 64.f) - mu * mu, 0.f);
    float inv = rsqrtf(var + 1e-5f);
    float4* op = (float4*)(out + (size_t)(R0 + rl) * 64 + c0);
#pragma unroll
    for (int qq = 0; qq < 4; ++qq) {
      float4 o;
      o.x = fmaxf((v[qq * 4 + 0] - mu) * inv * gamL[c0 + qq * 4 + 0] + betL[c0 + qq * 4 + 0], 0.f);
      o.y = fmaxf((v[qq * 4 + 1] - mu) * inv * gamL[c0 + qq * 4 + 1] + betL[c0 + qq * 4 + 1], 0.f);
      o.z = fmaxf((v[qq * 4 + 2] - mu) * inv * gamL[c0 + qq * 4 + 2] + betL[c0 + qq * 4 + 2], 0.f);
      o.w = fmaxf((v[qq * 4 + 3] - mu) * inv * gamL[c0 + qq * 4 + 3] + betL[c0 + qq * 4 + 3], 0.f);
      op[qq] = o;
    }
  }
}

extern "C" void kernel_launch(void* const* d_in, const int* in_sizes, int n_in,
                              void* d_out, int out_size, void* d_ws, size_t ws_size,
                              hipStream_t stream) {
  const float* X     = (const float*)d_in[0];
  const int*   adj   = (const int*)d_in[1];
  const float* Wself = (const float*)d_in[2];
  const float* bself = (const float*)d_in[3];
  const float* Wnb   = (const float*)d_in[4];
  const float* bnb   = (const float*)d_in[5];
  // d_in[6] = a_src : cancels in softmax -> unused
  const float* adst  = (const float*)d_in[7];
  // d_in[8] = b_att : cancels in softmax -> unused
  const float* gam   = (const float*)d_in[9];
  const float* bet   = (const float*)d_in[10];
  float* out = (float*)d_out;
  char* ws = (char*)d_ws;

  u16* Apad = (u16*)(ws);                    // 896*832  bf16 = 1,490,944 B
  u16* W2g  = (u16*)(ws + 1490944);          // 64*128   bf16 =    16,384 B
  u16* Bt   = (u16*)(ws + 1507328);          // 4224*832 bf16 = 7,028,736 B
  u16* Zb   = (u16*)(ws + 8536064);          // 896*4224 bf16 = 7,569,408 B (end 16,105,472)

  k_prep<<<dim3(365),  dim3(256), 0, stream>>>(adj, Wself, Wnb, Apad, W2g);
  k_b1t <<<dim3(845),  dim3(256), 0, stream>>>(X, adst, Bt);
  k_gemm<<<dim3(462),  dim3(512), 0, stream>>>(Apad, Bt, Zb);
  k_tail<<<dim3(784),  dim3(256), 0, stream>>>(X, Zb, W2g, bself, bnb, gam, bet, out);
}

// Round 7
// 34.919 us; speedup vs baseline: 2.0079x; 1.2022x over previous
//
#include <hip/hip_runtime.h>

// GraphConvLayer on MI355X (gfx950). f32 I/O, bf16 inside MFMA.
// softmax_j(src_i+dst_j+b) over neighbors == e_j/sum(e)  (src_i, b cancel).
//   Bt[n][k]: n=b*64+f -> bf16(e_bj * X[b,j,f]) (k=j); n=4096+b -> bf16(e_bj)
//   k_gt (fused): per block (64 nodes x 2 batches):
//     acc = A_tile @ Bt^T (K=832, dbuf global_load_lds, 1 barrier/step)
//     den via extra B-frag rows 4096+2bp.. (waves 3,7)
//     AB2 = [bf16(X) | bf16(acc/den)] (LDS, K=128) ; out = relu(LN(AB2@W2^T + bias))

typedef unsigned short u16;
typedef unsigned int u32;
typedef short bf16x8 __attribute__((ext_vector_type(8)));
typedef float f32x4 __attribute__((ext_vector_type(4)));

#define NNODE 784
#define MP 832      // K of big GEMM (padded node count)
#define BUFU 13312  // u16 per dbuf: A 64x64 (4096) + B 144x64 (9216)

__device__ __forceinline__ float b2f(u16 h) {
  union { u32 u; float f; } v; v.u = ((u32)h) << 16; return v.f;
}
__device__ __forceinline__ u16 f2b(float f) {
  union { float f; u32 u; } v; v.f = f;
  u32 r = (v.u + 0x7FFFu + ((v.u >> 16) & 1u)) >> 16;
  return (u16)r;
}
__device__ __forceinline__ void gload16(const u16* g, u16* l) {
  __builtin_amdgcn_global_load_lds((const __attribute__((address_space(1))) u32*)g,
                                   (__attribute__((address_space(3))) u32*)l, 16, 0, 0);
}

// ---------- K1: A int32->bf16 0/1 padded 896x832 ; W2g = [Ws|Wn] bf16, pre-inverse-swizzled ----------
__global__ __launch_bounds__(256) void k_prep(const int* __restrict__ adj,
                                              const float* __restrict__ Ws,
                                              const float* __restrict__ Wn,
                                              u16* __restrict__ A,
                                              u16* __restrict__ W2) {
  int t = threadIdx.x;
  if (blockIdx.x < 364) {                     // 364*256*8 = 896*832 elements
    int idx8 = blockIdx.x * 256 + t;
    int i = idx8 / 104, j8 = idx8 - i * 104;
    __align__(16) u16 o[8];
    if (i < NNODE && j8 < 98) {               // 98*8 = 784
      const int4* ap = (const int4*)(adj + (size_t)i * NNODE + j8 * 8);
      int4 a0 = ap[0], a1 = ap[1];
      o[0] = a0.x ? 0x3F80 : 0; o[1] = a0.y ? 0x3F80 : 0;
      o[2] = a0.z ? 0x3F80 : 0; o[3] = a0.w ? 0x3F80 : 0;
      o[4] = a1.x ? 0x3F80 : 0; o[5] = a1.y ? 0x3F80 : 0;
      o[6] = a1.z ? 0x3F80 : 0; o[7] = a1.w ? 0x3F80 : 0;
    } else {
#pragma unroll
      for (int q = 0; q < 8; ++q) o[q] = 0;
    }
    *(uint4*)(A + (size_t)i * MP + j8 * 8) = *(const uint4*)o;
  } else {                                    // block 364: W2 inverse-swizzled chunks
    int f = t >> 2, cq = t & 3;
#pragma unroll
    for (int q = 0; q < 4; ++q) {
      int c = cq * 4 + q;                     // dest chunk 0..15 (8 u16 each)
      int cs = c ^ (f & 7);                   // source chunk (stays within half)
      const float* src = (cs < 8) ? (Ws + f * 64 + cs * 8) : (Wn + f * 64 + (cs - 8) * 8);
      float4 v0 = ((const float4*)src)[0], v1 = ((const float4*)src)[1];
      __align__(16) u16 ob[8];
      ob[0] = f2b(v0.x); ob[1] = f2b(v0.y); ob[2] = f2b(v0.z); ob[3] = f2b(v0.w);
      ob[4] = f2b(v1.x); ob[5] = f2b(v1.y); ob[6] = f2b(v1.z); ob[7] = f2b(v1.w);
      *(uint4*)(W2 + f * 128 + c * 8) = *(const uint4*)ob;
    }
  }
}

// ---------- K2: fused e + transpose-scale into Bt[4224][832] ----------
__global__ __launch_bounds__(256) void k_b1t(const float* __restrict__ X,
                                             const float* __restrict__ adst,
                                             u16* __restrict__ Bt) {
  __shared__ float Xs[64][68];
  __shared__ float ad[64];
  __shared__ float es[64];
  int bid = blockIdx.x;
  int b = bid / 13, jt = bid - b * 13;
  int j0 = jt * 64;
  int t = threadIdx.x;
  if (b == 64) {                              // zero pad rows 4160..4223
    int row = 4160 + (t >> 2), c = (t & 3) * 16;
    uint4 z; z.x = 0; z.y = 0; z.z = 0; z.w = 0;
    uint4* p = (uint4*)(Bt + (size_t)row * MP + j0 + c);
    p[0] = z; p[1] = z;
    return;
  }
  int jr = t >> 2, cg = t & 3;
  {
    int j = j0 + jr;
    float4 z4; z4.x = 0.f; z4.y = 0.f; z4.z = 0.f; z4.w = 0.f;
    float4 v0 = z4, v1 = z4, v2 = z4, v3 = z4;
    if (j < NNODE) {
      const float4* xp = (const float4*)(X + ((size_t)b * NNODE + j) * 64 + cg * 16);
      v0 = xp[0]; v1 = xp[1]; v2 = xp[2]; v3 = xp[3];
    }
    float4* d = (float4*)&Xs[jr][cg * 16];
    d[0] = v0; d[1] = v1; d[2] = v2; d[3] = v3;
  }
  if (t < 64) ad[t] = adst[t];
  __syncthreads();
  {
    float dot = 0.f;
#pragma unroll
    for (int q = 0; q < 16; ++q) dot += Xs[jr][cg * 16 + q] * ad[cg * 16 + q];
    dot += __shfl_xor(dot, 1);
    dot += __shfl_xor(dot, 2);
    if (cg == 0) es[jr] = (j0 + jr < NNODE) ? __expf(dot) : 0.f;
  }
  __syncthreads();
  {
    int f = t >> 2, jc = (t & 3) * 16;
    __align__(16) u16 ob[16];
#pragma unroll
    for (int q = 0; q < 16; ++q) ob[q] = f2b(es[jc + q] * Xs[jc + q][f]);
    u16* op = Bt + ((size_t)b * 64 + f) * MP + j0 + jc;
    *(uint4*)op = *(const uint4*)ob;
    *(uint4*)(op + 8) = *(const uint4*)(ob + 8);
  }
  if (t < 64) Bt[(size_t)(4096 + b) * MP + j0 + t] = f2b(es[t]);
}

// ---------- K3: fused GEMM + tail ----------
__global__ __launch_bounds__(512) void k_gt(const u16* __restrict__ A,
                                            const u16* __restrict__ Bt,
                                            const u16* __restrict__ W2g,
                                            const float* __restrict__ X,
                                            const float* __restrict__ bs,
                                            const float* __restrict__ bn,
                                            const float* __restrict__ gam,
                                            const float* __restrict__ bet,
                                            float* __restrict__ out) {
  __shared__ __align__(16) u16 lds[2 * BUFU];   // 52 KB dbuf; post-loop union: AB2(32K)+W2(16K)
  __shared__ float denL[64][2];
  __shared__ float bsL[64], bnL[64], gamL[64], betL[64];
  const int t = threadIdx.x;
  const int l = t & 63, w = t >> 6;             // 8 waves
  const int g = l >> 4, l15 = l & 15;
  const int wr = w >> 2, wc = w & 3;            // first gemm: 32x32 per wave

  int wg = (blockIdx.x & 7) * 52 + (blockIdx.x >> 3);   // 416 = 8*52 bijective XCD swizzle
  const int bp = wg / 13;                       // batch pair 0..31 (it-major per XCD)
  const int it = wg - bp * 13;
  const int i0 = it * 64;
  const int nb0 = bp * 128;                     // Bt feat rows
  const int nd0 = 4096 + 2 * bp;                // Bt denom rows

  if (t < 64) { bsL[t] = bs[t]; bnL[t] = bn[t]; gamL[t] = gam[t]; betL[t] = bet[t]; }

  f32x4 acc[2][2];
#pragma unroll
  for (int mi = 0; mi < 2; ++mi)
#pragma unroll
    for (int ni = 0; ni < 2; ++ni) acc[mi][ni] = (f32x4){0.f, 0.f, 0.f, 0.f};
  f32x4 accD[2];
  accD[0] = (f32x4){0.f, 0.f, 0.f, 0.f};
  accD[1] = (f32x4){0.f, 0.f, 0.f, 0.f};

#define STAGE(kt_, buf_)                                                          \
  {                                                                               \
    int k0_ = (kt_) * 64;                                                         \
    u16* dA_ = lds + (buf_) * BUFU;                                               \
    u16* dB_ = dA_ + 4096;                                                        \
    { int r_ = t >> 3, c_ = t & 7;                                                \
      gload16(A + (size_t)(i0 + r_) * MP + k0_ + ((c_ ^ (r_ & 7)) * 8),           \
              dA_ + w * 512); }                                                   \
    _Pragma("unroll")                                                             \
    for (int h_ = 0; h_ < 2; ++h_) {                                              \
      int s_ = h_ * 512 + t; int r_ = s_ >> 3, c_ = s_ & 7;                       \
      gload16(Bt + (size_t)(nb0 + r_) * MP + k0_ + ((c_ ^ (r_ & 7)) * 8),         \
              dB_ + h_ * 4096 + w * 512); }                                       \
    if (w < 2) { int r_ = t >> 3, c_ = t & 7;                                     \
      gload16(Bt + (size_t)(nd0 + r_) * MP + k0_ + ((c_ ^ (r_ & 7)) * 8),         \
              dB_ + 8192 + w * 512); }                                            \
  }

  STAGE(0, 0);
  __syncthreads();

  for (int kt = 0; kt < 13; ++kt) {
    int buf = kt & 1;
    if (kt < 12) STAGE(kt + 1, buf ^ 1);        // lands during MFMA phase
    const u16* As = lds + buf * BUFU;
    const u16* Bs = As + 4096;
#pragma unroll
    for (int kk = 0; kk < 2; ++kk) {
      int q = kk * 4 + g;
      bf16x8 af[2], bfr[2];
#pragma unroll
      for (int mi = 0; mi < 2; ++mi) {
        int ra = wr * 32 + mi * 16 + l15;
        af[mi] = *(const bf16x8*)(As + ra * 64 + ((q ^ (ra & 7)) * 8));
      }
#pragma unroll
      for (int ni = 0; ni < 2; ++ni) {
        int rb = wc * 32 + ni * 16 + l15;
        bfr[ni] = *(const bf16x8*)(Bs + rb * 64 + ((q ^ (rb & 7)) * 8));
      }
#pragma unroll
      for (int mi = 0; mi < 2; ++mi)
#pragma unroll
        for (int ni = 0; ni < 2; ++ni)
          acc[mi][ni] = __builtin_amdgcn_mfma_f32_16x16x32_bf16(af[mi], bfr[ni], acc[mi][ni], 0, 0, 0);
      if (wc == 3) {                            // waves 3,7: denominator fragment
        int rd = 128 + l15;
        bf16x8 bd = *(const bf16x8*)(Bs + rd * 64 + ((q ^ (rd & 7)) * 8));
        accD[0] = __builtin_amdgcn_mfma_f32_16x16x32_bf16(af[0], bd, accD[0], 0, 0, 0);
        accD[1] = __builtin_amdgcn_mfma_f32_16x16x32_bf16(af[1], bd, accD[1], 0, 0, 0);
      }
    }
    __syncthreads();
  }
#undef STAGE

  // ---- P1: den -> LDS ; X -> AB2 chunks 0..7 ; W2 -> LDS (linear copy, pre-swz src)
  u16* AB2 = lds;                               // [128 rows][128 u16] swizzled
  u16* W2l = lds + 16384;                       // [64 rows][128 u16] swizzled
  if (wc == 3 && l15 < 2) {
#pragma unroll
    for (int mi = 0; mi < 2; ++mi)
#pragma unroll
      for (int j = 0; j < 4; ++j)
        denL[wr * 32 + mi * 16 + g * 4 + j][l15] = accD[mi][j];
  }
#pragma unroll
  for (int q2 = 0; q2 < 2; ++q2) {
    int s = q2 * 512 + t;
    int r = s >> 3, c = s & 7;                  // AB2 row, X-chunk
    int i = i0 + (r & 63);
    int bq = bp * 2 + (r >> 6);
    float4 v0, v1;
    v0.x = v0.y = v0.z = v0.w = 0.f; v1 = v0;
    if (i < NNODE) {
      const float4* xp = (const float4*)(X + ((size_t)bq * NNODE + i) * 64 + c * 8);
      v0 = xp[0]; v1 = xp[1];
    }
    __align__(16) u16 ob[8];
    ob[0] = f2b(v0.x); ob[1] = f2b(v0.y); ob[2] = f2b(v0.z); ob[3] = f2b(v0.w);
    ob[4] = f2b(v1.x); ob[5] = f2b(v1.y); ob[6] = f2b(v1.z); ob[7] = f2b(v1.w);
    *(uint4*)(AB2 + r * 128 + ((c ^ (r & 7)) * 8)) = *(const uint4*)ob;
  }
#pragma unroll
  for (int q2 = 0; q2 < 2; ++q2)
    gload16(W2g + q2 * 4096 + w * 512 + l * 8, W2l + q2 * 4096 + w * 512);
  __syncthreads();

  // ---- P2: Zs = acc/den -> AB2 chunks 8..15
#pragma unroll
  for (int mi = 0; mi < 2; ++mi)
#pragma unroll
    for (int ni = 0; ni < 2; ++ni) {
      int col = wc * 32 + ni * 16 + l15;
      int b2 = col >> 6, f = col & 63;
#pragma unroll
      for (int j = 0; j < 4; ++j) {
        int ri = wr * 32 + mi * 16 + g * 4 + j;
        float d = denL[ri][b2];
        float rd = d > 0.f ? 1.f / d : 0.f;
        int R = b2 * 64 + ri;
        AB2[R * 128 + (((8 + (f >> 3)) ^ (R & 7)) * 8) + (f & 7)] = f2b(acc[mi][ni][j] * rd);
      }
    }
  __syncthreads();

  // ---- P3: second gemm: per batch 64x64, K=128 ; wave = (batch w>>2, m-frag w&3)
  const int b2w = w >> 2, mf = w & 3;
  f32x4 a2[4];
#pragma unroll
  for (int nf = 0; nf < 4; ++nf) a2[nf] = (f32x4){0.f, 0.f, 0.f, 0.f};
#pragma unroll
  for (int kk = 0; kk < 4; ++kk) {
    int q2 = kk * 4 + g;
    int ra = b2w * 64 + mf * 16 + l15;
    bf16x8 af = *(const bf16x8*)(AB2 + ra * 128 + ((q2 ^ (ra & 7)) * 8));
#pragma unroll
    for (int nf = 0; nf < 4; ++nf) {
      int rb = nf * 16 + l15;
      bf16x8 bfw = *(const bf16x8*)(W2l + rb * 128 + ((q2 ^ (rb & 7)) * 8));
      a2[nf] = __builtin_amdgcn_mfma_f32_16x16x32_bf16(af, bfw, a2[nf], 0, 0, 0);
    }
  }

  // ---- P4: bias + LN + ReLU + guarded store
#pragma unroll
  for (int j = 0; j < 4; ++j) {
    int ri = mf * 16 + g * 4 + j;
    float d = denL[ri][b2w];
    float bnm = d > 0.f ? 1.f : 0.f;
    float v0 = a2[0][j] + bsL[l15]      + bnm * bnL[l15];
    float v1 = a2[1][j] + bsL[l15 + 16] + bnm * bnL[l15 + 16];
    float v2 = a2[2][j] + bsL[l15 + 32] + bnm * bnL[l15 + 32];
    float v3 = a2[3][j] + bsL[l15 + 48] + bnm * bnL[l15 + 48];
    float s1 = v0 + v1 + v2 + v3;
    float s2 = v0 * v0 + v1 * v1 + v2 * v2 + v3 * v3;
    s1 += __shfl_xor(s1, 1); s2 += __shfl_xor(s2, 1);
    s1 += __shfl_xor(s1, 2); s2 += __shfl_xor(s2, 2);
    s1 += __shfl_xor(s1, 4); s2 += __shfl_xor(s2, 4);
    s1 += __shfl_xor(s1, 8); s2 += __shfl_xor(s2, 8);
    float mu = s1 * (1.f / 64.f);
    float var = fmaxf(s2 * (1.f / 64.f) - mu * mu, 0.f);
    float inv = rsqrtf(var + 1e-5f);
    int node = i0 + ri;
    if (node < NNODE) {
      float* op = out + ((size_t)(bp * 2 + b2w) * NNODE + node) * 64;
      op[l15]      = fmaxf((v0 - mu) * inv * gamL[l15]      + betL[l15],      0.f);
      op[l15 + 16] = fmaxf((v1 - mu) * inv * gamL[l15 + 16] + betL[l15 + 16], 0.f);
      op[l15 + 32] = fmaxf((v2 - mu) * inv * gamL[l15 + 32] + betL[l15 + 32], 0.f);
      op[l15 + 48] = fmaxf((v3 - mu) * inv * gamL[l15 + 48] + betL[l15 + 48], 0.f);
    }
  }
}

extern "C" void kernel_launch(void* const* d_in, const int* in_sizes, int n_in,
                              void* d_out, int out_size, void* d_ws, size_t ws_size,
                              hipStream_t stream) {
  const float* X     = (const float*)d_in[0];
  const int*   adj   = (const int*)d_in[1];
  const float* Wself = (const float*)d_in[2];
  const float* bself = (const float*)d_in[3];
  const float* Wnb   = (const float*)d_in[4];
  const float* bnb   = (const float*)d_in[5];
  // d_in[6] = a_src : cancels in softmax -> unused
  const float* adst  = (const float*)d_in[7];
  // d_in[8] = b_att : cancels in softmax -> unused
  const float* gam   = (const float*)d_in[9];
  const float* bet   = (const float*)d_in[10];
  float* out = (float*)d_out;
  char* ws = (char*)d_ws;

  u16* Apad = (u16*)(ws);                    // 896*832  bf16 = 1,490,944 B
  u16* W2g  = (u16*)(ws + 1490944);          // 64*128   bf16 =    16,384 B
  u16* Bt   = (u16*)(ws + 1507328);          // 4224*832 bf16 = 7,028,736 B (end 8,536,064)

  k_prep<<<dim3(365), dim3(256), 0, stream>>>(adj, Wself, Wnb, Apad, W2g);
  k_b1t <<<dim3(845), dim3(256), 0, stream>>>(X, adst, Bt);
  k_gt  <<<dim3(416), dim3(512), 0, stream>>>(Apad, Bt, W2g, X, bself, bnb, gam, bet, out);
}

// Round 8
// 30.199 us; speedup vs baseline: 2.3218x; 1.1563x over previous
//
#include <hip/hip_runtime.h>

// GraphConvLayer on MI355X (gfx950). f32 I/O, bf16 inside MFMA.
// softmax_j(src_i+dst_j+b) over neighbors == e_j/sum(e)  (src_i, b cancel).
//   Bt[n][k]: n=b*64+f -> bf16(e_bj * X[b,j,f]) (k=j); n=4096+b -> bf16(e_bj)
//   k_gt (fused): per block (64 nodes x 2 batches):
//     acc = A_tile @ Bt^T (K=832, dbuf global_load_lds, 1 barrier/step)
//     den via extra B-frag rows 4096+2bp (kk=0 -> waves wc==2, kk=1 -> wc==3)
//     AB2 = [bf16(X) | bf16(acc/den)] (LDS, K=128) ; out = relu(LN(AB2@W2^T + bias))
// k_pre = k_prep + k_b1t merged (saves one ~4.5us launch boundary).

typedef unsigned short u16;
typedef unsigned int u32;
typedef short bf16x8 __attribute__((ext_vector_type(8)));
typedef float f32x4 __attribute__((ext_vector_type(4)));

#define NNODE 784
#define MP 832      // K of big GEMM (padded node count)
#define BUFU 13312  // u16 per dbuf: A 64x64 (4096) + B 144x64 (9216)

__device__ __forceinline__ float b2f(u16 h) {
  union { u32 u; float f; } v; v.u = ((u32)h) << 16; return v.f;
}
__device__ __forceinline__ u16 f2b(float f) {
  union { float f; u32 u; } v; v.f = f;
  u32 r = (v.u + 0x7FFFu + ((v.u >> 16) & 1u)) >> 16;
  return (u16)r;
}
__device__ __forceinline__ void gload16(const u16* g, u16* l) {
  __builtin_amdgcn_global_load_lds((const __attribute__((address_space(1))) u32*)g,
                                   (__attribute__((address_space(3))) u32*)l, 16, 0, 0);
}

// ---------- K1 (merged): A-convert (bid<364) | W2 build (bid==364) | b1t (bid>=365) ----------
__global__ __launch_bounds__(256) void k_pre(const int* __restrict__ adj,
                                             const float* __restrict__ Ws,
                                             const float* __restrict__ Wn,
                                             const float* __restrict__ X,
                                             const float* __restrict__ adst,
                                             u16* __restrict__ A,
                                             u16* __restrict__ W2,
                                             u16* __restrict__ Bt) {
  const int bid = blockIdx.x;
  const int t = threadIdx.x;
  if (bid < 364) {                            // A: int32 -> bf16 0/1, padded 896x832
    int idx8 = bid * 256 + t;
    int i = idx8 / 104, j8 = idx8 - i * 104;
    __align__(16) u16 o[8];
    if (i < NNODE && j8 < 98) {               // 98*8 = 784
      const int4* ap = (const int4*)(adj + (size_t)i * NNODE + j8 * 8);
      int4 a0 = ap[0], a1 = ap[1];
      o[0] = a0.x ? 0x3F80 : 0; o[1] = a0.y ? 0x3F80 : 0;
      o[2] = a0.z ? 0x3F80 : 0; o[3] = a0.w ? 0x3F80 : 0;
      o[4] = a1.x ? 0x3F80 : 0; o[5] = a1.y ? 0x3F80 : 0;
      o[6] = a1.z ? 0x3F80 : 0; o[7] = a1.w ? 0x3F80 : 0;
    } else {
#pragma unroll
      for (int q = 0; q < 8; ++q) o[q] = 0;
    }
    *(uint4*)(A + (size_t)i * MP + j8 * 8) = *(const uint4*)o;
    return;
  }
  if (bid == 364) {                           // W2: [Ws|Wn] bf16, pre-inverse-swizzled
    int f = t >> 2, cq = t & 3;
#pragma unroll
    for (int q = 0; q < 4; ++q) {
      int c = cq * 4 + q;                     // dest chunk 0..15 (8 u16 each)
      int cs = c ^ (f & 7);                   // source chunk (stays within half)
      const float* src = (cs < 8) ? (Ws + f * 64 + cs * 8) : (Wn + f * 64 + (cs - 8) * 8);
      float4 v0 = ((const float4*)src)[0], v1 = ((const float4*)src)[1];
      __align__(16) u16 ob[8];
      ob[0] = f2b(v0.x); ob[1] = f2b(v0.y); ob[2] = f2b(v0.z); ob[3] = f2b(v0.w);
      ob[4] = f2b(v1.x); ob[5] = f2b(v1.y); ob[6] = f2b(v1.z); ob[7] = f2b(v1.w);
      *(uint4*)(W2 + f * 128 + c * 8) = *(const uint4*)ob;
    }
    return;
  }
  // ---- b1t: fused e + transpose-scale into Bt[4224][832]
  __shared__ float Xs[64][68];
  __shared__ float ad[64];
  __shared__ float es[64];
  int bid2 = bid - 365;
  int b = bid2 / 13, jt = bid2 - b * 13;
  int j0 = jt * 64;
  if (b == 64) {                              // zero pad rows 4160..4223
    int row = 4160 + (t >> 2), c = (t & 3) * 16;
    uint4 z; z.x = 0; z.y = 0; z.z = 0; z.w = 0;
    uint4* p = (uint4*)(Bt + (size_t)row * MP + j0 + c);
    p[0] = z; p[1] = z;
    return;
  }
  int jr = t >> 2, cg = t & 3;
  {
    int j = j0 + jr;
    float4 z4; z4.x = 0.f; z4.y = 0.f; z4.z = 0.f; z4.w = 0.f;
    float4 v0 = z4, v1 = z4, v2 = z4, v3 = z4;
    if (j < NNODE) {
      const float4* xp = (const float4*)(X + ((size_t)b * NNODE + j) * 64 + cg * 16);
      v0 = xp[0]; v1 = xp[1]; v2 = xp[2]; v3 = xp[3];
    }
    float4* d = (float4*)&Xs[jr][cg * 16];
    d[0] = v0; d[1] = v1; d[2] = v2; d[3] = v3;
  }
  if (t < 64) ad[t] = adst[t];
  __syncthreads();
  {
    float dot = 0.f;
#pragma unroll
    for (int q = 0; q < 16; ++q) dot += Xs[jr][cg * 16 + q] * ad[cg * 16 + q];
    dot += __shfl_xor(dot, 1);
    dot += __shfl_xor(dot, 2);
    if (cg == 0) es[jr] = (j0 + jr < NNODE) ? __expf(dot) : 0.f;
  }
  __syncthreads();
  {
    int f = t >> 2, jc = (t & 3) * 16;
    __align__(16) u16 ob[16];
#pragma unroll
    for (int q = 0; q < 16; ++q) ob[q] = f2b(es[jc + q] * Xs[jc + q][f]);
    u16* op = Bt + ((size_t)b * 64 + f) * MP + j0 + jc;
    *(uint4*)op = *(const uint4*)ob;
    *(uint4*)(op + 8) = *(const uint4*)(ob + 8);
  }
  if (t < 64) Bt[(size_t)(4096 + b) * MP + j0 + t] = f2b(es[t]);
}

// ---------- K2: fused GEMM + tail ----------
__global__ __launch_bounds__(512, 4) void k_gt(const u16* __restrict__ A,
                                               const u16* __restrict__ Bt,
                                               const u16* __restrict__ W2g,
                                               const float* __restrict__ X,
                                               const float* __restrict__ bs,
                                               const float* __restrict__ bn,
                                               const float* __restrict__ gam,
                                               const float* __restrict__ bet,
                                               float* __restrict__ out) {
  __shared__ __align__(16) u16 lds[2 * BUFU];   // 52 KB dbuf; post-loop union: AB2(32K)+W2(16K)
  __shared__ float denL[64][2];
  __shared__ float bsL[64], bnL[64], gamL[64], betL[64];
  const int t = threadIdx.x;
  const int l = t & 63, w = t >> 6;             // 8 waves
  const int g = l >> 4, l15 = l & 15;
  const int wr = w >> 2, wc = w & 3;            // first gemm: 32x32 per wave

  int wg = (blockIdx.x & 7) * 52 + (blockIdx.x >> 3);   // 416 = 8*52 bijective XCD swizzle
  const int bp = wg / 13;                       // batch pair 0..31 (it-major per XCD)
  const int it = wg - bp * 13;
  const int i0 = it * 64;
  const int nb0 = bp * 128;                     // Bt feat rows
  const int nd0 = 4096 + 2 * bp;                // Bt denom rows

  if (t < 64) { bsL[t] = bs[t]; bnL[t] = bn[t]; gamL[t] = gam[t]; betL[t] = bet[t]; }

  f32x4 acc[2][2];
#pragma unroll
  for (int mi = 0; mi < 2; ++mi)
#pragma unroll
    for (int ni = 0; ni < 2; ++ni) acc[mi][ni] = (f32x4){0.f, 0.f, 0.f, 0.f};
  f32x4 accD[2];
  accD[0] = (f32x4){0.f, 0.f, 0.f, 0.f};
  accD[1] = (f32x4){0.f, 0.f, 0.f, 0.f};

#define STAGE(kt_, buf_)                                                          \
  {                                                                               \
    int k0_ = (kt_) * 64;                                                         \
    u16* dA_ = lds + (buf_) * BUFU;                                               \
    u16* dB_ = dA_ + 4096;                                                        \
    { int r_ = t >> 3, c_ = t & 7;                                                \
      gload16(A + (size_t)(i0 + r_) * MP + k0_ + ((c_ ^ (r_ & 7)) * 8),           \
              dA_ + w * 512); }                                                   \
    _Pragma("unroll")                                                             \
    for (int h_ = 0; h_ < 2; ++h_) {                                              \
      int s_ = h_ * 512 + t; int r_ = s_ >> 3, c_ = s_ & 7;                       \
      gload16(Bt + (size_t)(nb0 + r_) * MP + k0_ + ((c_ ^ (r_ & 7)) * 8),         \
              dB_ + h_ * 4096 + w * 512); }                                       \
    if (w < 2) { int r_ = t >> 3, c_ = t & 7;                                     \
      gload16(Bt + (size_t)(nd0 + r_) * MP + k0_ + ((c_ ^ (r_ & 7)) * 8),         \
              dB_ + 8192 + w * 512); }                                            \
  }

  STAGE(0, 0);
  __syncthreads();

  for (int kt = 0; kt < 13; ++kt) {
    int buf = kt & 1;
    if (kt < 12) STAGE(kt + 1, buf ^ 1);        // lands during MFMA phase
    const u16* As = lds + buf * BUFU;
    const u16* Bs = As + 4096;
#pragma unroll
    for (int kk = 0; kk < 2; ++kk) {
      int q = kk * 4 + g;
      bf16x8 af[2], bfr[2];
#pragma unroll
      for (int mi = 0; mi < 2; ++mi) {
        int ra = wr * 32 + mi * 16 + l15;
        af[mi] = *(const bf16x8*)(As + ra * 64 + ((q ^ (ra & 7)) * 8));
      }
#pragma unroll
      for (int ni = 0; ni < 2; ++ni) {
        int rb = wc * 32 + ni * 16 + l15;
        bfr[ni] = *(const bf16x8*)(Bs + rb * 64 + ((q ^ (rb & 7)) * 8));
      }
#pragma unroll
      for (int mi = 0; mi < 2; ++mi)
#pragma unroll
        for (int ni = 0; ni < 2; ++ni)
          acc[mi][ni] = __builtin_amdgcn_mfma_f32_16x16x32_bf16(af[mi], bfr[ni], acc[mi][ni], 0, 0, 0);
      if (wc == 2 + kk) {                       // den: kk=0 -> wc2, kk=1 -> wc3 (balanced)
        int rd = 128 + l15;
        bf16x8 bd = *(const bf16x8*)(Bs + rd * 64 + ((q ^ (rd & 7)) * 8));
        accD[0] = __builtin_amdgcn_mfma_f32_16x16x32_bf16(af[0], bd, accD[0], 0, 0, 0);
        accD[1] = __builtin_amdgcn_mfma_f32_16x16x32_bf16(af[1], bd, accD[1], 0, 0, 0);
      }
    }
    __syncthreads();
  }
#undef STAGE

  // ---- P1: den partial (wc2) -> LDS ; X -> AB2 chunks 0..7 ; W2 -> LDS
  u16* AB2 = lds;                               // [128 rows][128 u16] swizzled
  u16* W2l = lds + 16384;                       // [64 rows][128 u16] swizzled
  if (wc == 2 && l15 < 2) {
#pragma unroll
    for (int mi = 0; mi < 2; ++mi)
#pragma unroll
      for (int j = 0; j < 4; ++j)
        denL[wr * 32 + mi * 16 + g * 4 + j][l15] = accD[mi][j];
  }
#pragma unroll
  for (int q2 = 0; q2 < 2; ++q2) {
    int s = q2 * 512 + t;
    int r = s >> 3, c = s & 7;                  // AB2 row, X-chunk
    int i = i0 + (r & 63);
    int bq = bp * 2 + (r >> 6);
    float4 v0, v1;
    v0.x = v0.y = v0.z = v0.w = 0.f; v1 = v0;
    if (i < NNODE) {
      const float4* xp = (const float4*)(X + ((size_t)bq * NNODE + i) * 64 + c * 8);
      v0 = xp[0]; v1 = xp[1];
    }
    __align__(16) u16 ob[8];
    ob[0] = f2b(v0.x); ob[1] = f2b(v0.y); ob[2] = f2b(v0.z); ob[3] = f2b(v0.w);
    ob[4] = f2b(v1.x); ob[5] = f2b(v1.y); ob[6] = f2b(v1.z); ob[7] = f2b(v1.w);
    *(uint4*)(AB2 + r * 128 + ((c ^ (r & 7)) * 8)) = *(const uint4*)ob;
  }
#pragma unroll
  for (int q2 = 0; q2 < 2; ++q2)
    gload16(W2g + q2 * 4096 + w * 512 + l * 8, W2l + q2 * 4096 + w * 512);
  __syncthreads();

  // ---- P1b: den partial (wc3) accumulate
  if (wc == 3 && l15 < 2) {
#pragma unroll
    for (int mi = 0; mi < 2; ++mi)
#pragma unroll
      for (int j = 0; j < 4; ++j)
        denL[wr * 32 + mi * 16 + g * 4 + j][l15] += accD[mi][j];
  }
  __syncthreads();

  // ---- P2: Zs = acc/den -> AB2 chunks 8..15
#pragma unroll
  for (int mi = 0; mi < 2; ++mi)
#pragma unroll
    for (int ni = 0; ni < 2; ++ni) {
      int col = wc * 32 + ni * 16 + l15;
      int b2 = col >> 6, f = col & 63;
#pragma unroll
      for (int j = 0; j < 4; ++j) {
        int ri = wr * 32 + mi * 16 + g * 4 + j;
        float d = denL[ri][b2];
        float rd = d > 0.f ? 1.f / d : 0.f;
        int R = b2 * 64 + ri;
        AB2[R * 128 + (((8 + (f >> 3)) ^ (R & 7)) * 8) + (f & 7)] = f2b(acc[mi][ni][j] * rd);
      }
    }
  __syncthreads();

  // ---- P3: second gemm: per batch 64x64, K=128 ; wave = (batch w>>2, m-frag w&3)
  const int b2w = w >> 2, mf = w & 3;
  f32x4 a2[4];
#pragma unroll
  for (int nf = 0; nf < 4; ++nf) a2[nf] = (f32x4){0.f, 0.f, 0.f, 0.f};
#pragma unroll
  for (int kk = 0; kk < 4; ++kk) {
    int q2 = kk * 4 + g;
    int ra = b2w * 64 + mf * 16 + l15;
    bf16x8 af = *(const bf16x8*)(AB2 + ra * 128 + ((q2 ^ (ra & 7)) * 8));
#pragma unroll
    for (int nf = 0; nf < 4; ++nf) {
      int rb = nf * 16 + l15;
      bf16x8 bfw = *(const bf16x8*)(W2l + rb * 128 + ((q2 ^ (rb & 7)) * 8));
      a2[nf] = __builtin_amdgcn_mfma_f32_16x16x32_bf16(af, bfw, a2[nf], 0, 0, 0);
    }
  }

  // ---- P4: bias + LN + ReLU + guarded store
#pragma unroll
  for (int j = 0; j < 4; ++j) {
    int ri = mf * 16 + g * 4 + j;
    float d = denL[ri][b2w];
    float bnm = d > 0.f ? 1.f : 0.f;
    float v0 = a2[0][j] + bsL[l15]      + bnm * bnL[l15];
    float v1 = a2[1][j] + bsL[l15 + 16] + bnm * bnL[l15 + 16];
    float v2 = a2[2][j] + bsL[l15 + 32] + bnm * bnL[l15 + 32];
    float v3 = a2[3][j] + bsL[l15 + 48] + bnm * bnL[l15 + 48];
    float s1 = v0 + v1 + v2 + v3;
    float s2 = v0 * v0 + v1 * v1 + v2 * v2 + v3 * v3;
    s1 += __shfl_xor(s1, 1); s2 += __shfl_xor(s2, 1);
    s1 += __shfl_xor(s1, 2); s2 += __shfl_xor(s2, 2);
    s1 += __shfl_xor(s1, 4); s2 += __shfl_xor(s2, 4);
    s1 += __shfl_xor(s1, 8); s2 += __shfl_xor(s2, 8);
    float mu = s1 * (1.f / 64.f);
    float var = fmaxf(s2 * (1.f / 64.f) - mu * mu, 0.f);
    float inv = rsqrtf(var + 1e-5f);
    int node = i0 + ri;
    if (node < NNODE) {
      float* op = out + ((size_t)(bp * 2 + b2w) * NNODE + node) * 64;
      op[l15]      = fmaxf((v0 - mu) * inv * gamL[l15]      + betL[l15],      0.f);
      op[l15 + 16] = fmaxf((v1 - mu) * inv * gamL[l15 + 16] + betL[l15 + 16], 0.f);
      op[l15 + 32] = fmaxf((v2 - mu) * inv * gamL[l15 + 32] + betL[l15 + 32], 0.f);
      op[l15 + 48] = fmaxf((v3 - mu) * inv * gamL[l15 + 48] + betL[l15 + 48], 0.f);
    }
  }
}

extern "C" void kernel_launch(void* const* d_in, const int* in_sizes, int n_in,
                              void* d_out, int out_size, void* d_ws, size_t ws_size,
                              hipStream_t stream) {
  const float* X     = (const float*)d_in[0];
  const int*   adj   = (const int*)d_in[1];
  const float* Wself = (const float*)d_in[2];
  const float* bself = (const float*)d_in[3];
  const float* Wnb   = (const float*)d_in[4];
  const float* bnb   = (const float*)d_in[5];
  // d_in[6] = a_src : cancels in softmax -> unused
  const float* adst  = (const float*)d_in[7];
  // d_in[8] = b_att : cancels in softmax -> unused
  const float* gam   = (const float*)d_in[9];
  const float* bet   = (const float*)d_in[10];
  float* out = (float*)d_out;
  char* ws = (char*)d_ws;

  u16* Apad = (u16*)(ws);                    // 896*832  bf16 = 1,490,944 B
  u16* W2g  = (u16*)(ws + 1490944);          // 64*128   bf16 =    16,384 B
  u16* Bt   = (u16*)(ws + 1507328);          // 4224*832 bf16 = 7,028,736 B (end 8,536,064)

  k_pre<<<dim3(1210), dim3(256), 0, stream>>>(adj, Wself, Wnb, X, adst, Apad, W2g, Bt);
  k_gt <<<dim3(416),  dim3(512), 0, stream>>>(Apad, Bt, W2g, X, bself, bnb, gam, bet, out);
}

// Round 10
// 30.152 us; speedup vs baseline: 2.3253x; 1.0015x over previous
//
#include <hip/hip_runtime.h>

// GraphConvLayer on MI355X (gfx950). f32 I/O, bf16 inside MFMA.
// softmax_j(src_i+dst_j+b) over neighbors == e_j/sum(e)  (src_i, b cancel).
//   Bt[n][k]: n=b*64+f -> bf16(e_bj * X[b,j,f]) (k=j); n=4096+b -> bf16(e_bj)
//   Phase B per block (64 nodes x 2 batches): acc = A_tile @ Bt^T (K=832, dbuf
//   global_load_lds, 1 barrier/step); den via extra B-frag; AB2=[bf16(X)|bf16(acc/den)];
//   out = relu(LN(AB2@W2^T + bias)).
// Fused single-kernel path uses a manual device-scope spin barrier (counter in ws),
// guarded by a host occupancy query; falls back to the proven 2-kernel pipeline.

typedef unsigned short u16;
typedef unsigned int u32;
typedef short bf16x8 __attribute__((ext_vector_type(8)));
typedef float f32x4 __attribute__((ext_vector_type(4)));

#define NNODE 784
#define MP 832      // K of big GEMM (padded node count)
#define BUFU 13312  // u16 per dbuf: A 64x64 (4096) + B 144x64 (9216)

__device__ __forceinline__ float b2f(u16 h) {
  union { u32 u; float f; } v; v.u = ((u32)h) << 16; return v.f;
}
__device__ __forceinline__ u16 f2b(float f) {
  union { float f; u32 u; } v; v.f = f;
  u32 r = (v.u + 0x7FFFu + ((v.u >> 16) & 1u)) >> 16;
  return (u16)r;
}
__device__ __forceinline__ void gload16(const u16* g, u16* l) {
  __builtin_amdgcn_global_load_lds((const __attribute__((address_space(1))) u32*)g,
                                   (__attribute__((address_space(3))) u32*)l, 16, 0, 0);
}

// ======================= device bodies shared by both paths =======================

// ---- Phase-B body (identical math to round-8 k_gt) ----
__device__ __forceinline__ void phaseB(const u16* __restrict__ A,
                                       const u16* __restrict__ Bt,
                                       const u16* __restrict__ W2g,
                                       const float* __restrict__ X,
                                       float* __restrict__ out,
                                       u16* lds, float (*denL)[2],
                                       float* bsL, float* bnL, float* gamL, float* betL,
                                       int bid, int t) {
  const int l = t & 63, w = t >> 6;             // 8 waves
  const int g = l >> 4, l15 = l & 15;
  const int wr = w >> 2, wc = w & 3;            // first gemm: 32x32 per wave

  int wg = (bid & 7) * 52 + (bid >> 3);         // 416 = 8*52 bijective XCD swizzle
  const int bp = wg / 13;                       // batch pair 0..31 (it-major per XCD)
  const int it = wg - bp * 13;
  const int i0 = it * 64;
  const int nb0 = bp * 128;                     // Bt feat rows
  const int nd0 = 4096 + 2 * bp;                // Bt denom rows

  f32x4 acc[2][2];
#pragma unroll
  for (int mi = 0; mi < 2; ++mi)
#pragma unroll
    for (int ni = 0; ni < 2; ++ni) acc[mi][ni] = (f32x4){0.f, 0.f, 0.f, 0.f};
  f32x4 accD[2];
  accD[0] = (f32x4){0.f, 0.f, 0.f, 0.f};
  accD[1] = (f32x4){0.f, 0.f, 0.f, 0.f};

#define STAGE(kt_, buf_)                                                          \
  {                                                                               \
    int k0_ = (kt_) * 64;                                                         \
    u16* dA_ = lds + (buf_) * BUFU;                                               \
    u16* dB_ = dA_ + 4096;                                                        \
    { int r_ = t >> 3, c_ = t & 7;                                                \
      gload16(A + (size_t)(i0 + r_) * MP + k0_ + ((c_ ^ (r_ & 7)) * 8),           \
              dA_ + w * 512); }                                                   \
    _Pragma("unroll")                                                             \
    for (int h_ = 0; h_ < 2; ++h_) {                                              \
      int s_ = h_ * 512 + t; int r_ = s_ >> 3, c_ = s_ & 7;                       \
      gload16(Bt + (size_t)(nb0 + r_) * MP + k0_ + ((c_ ^ (r_ & 7)) * 8),         \
              dB_ + h_ * 4096 + w * 512); }                                       \
    if (w < 2) { int r_ = t >> 3, c_ = t & 7;                                     \
      gload16(Bt + (size_t)(nd0 + r_) * MP + k0_ + ((c_ ^ (r_ & 7)) * 8),         \
              dB_ + 8192 + w * 512); }                                            \
  }

  STAGE(0, 0);
  __syncthreads();

  for (int kt = 0; kt < 13; ++kt) {
    int buf = kt & 1;
    if (kt < 12) STAGE(kt + 1, buf ^ 1);        // lands during MFMA phase
    const u16* As = lds + buf * BUFU;
    const u16* Bs = As + 4096;
#pragma unroll
    for (int kk = 0; kk < 2; ++kk) {
      int q = kk * 4 + g;
      bf16x8 af[2], bfr[2];
#pragma unroll
      for (int mi = 0; mi < 2; ++mi) {
        int ra = wr * 32 + mi * 16 + l15;
        af[mi] = *(const bf16x8*)(As + ra * 64 + ((q ^ (ra & 7)) * 8));
      }
#pragma unroll
      for (int ni = 0; ni < 2; ++ni) {
        int rb = wc * 32 + ni * 16 + l15;
        bfr[ni] = *(const bf16x8*)(Bs + rb * 64 + ((q ^ (rb & 7)) * 8));
      }
#pragma unroll
      for (int mi = 0; mi < 2; ++mi)
#pragma unroll
        for (int ni = 0; ni < 2; ++ni)
          acc[mi][ni] = __builtin_amdgcn_mfma_f32_16x16x32_bf16(af[mi], bfr[ni], acc[mi][ni], 0, 0, 0);
      if (wc == 2 + kk) {                       // den: kk=0 -> wc2, kk=1 -> wc3
        int rd = 128 + l15;
        bf16x8 bd = *(const bf16x8*)(Bs + rd * 64 + ((q ^ (rd & 7)) * 8));
        accD[0] = __builtin_amdgcn_mfma_f32_16x16x32_bf16(af[0], bd, accD[0], 0, 0, 0);
        accD[1] = __builtin_amdgcn_mfma_f32_16x16x32_bf16(af[1], bd, accD[1], 0, 0, 0);
      }
    }
    __syncthreads();
  }
#undef STAGE

  // ---- P1: den partial (wc2) -> LDS ; X -> AB2 chunks 0..7 ; W2 -> LDS
  u16* AB2 = lds;                               // [128 rows][128 u16] swizzled
  u16* W2l = lds + 16384;                       // [64 rows][128 u16] swizzled
  if (wc == 2 && l15 < 2) {
#pragma unroll
    for (int mi = 0; mi < 2; ++mi)
#pragma unroll
      for (int j = 0; j < 4; ++j)
        denL[wr * 32 + mi * 16 + g * 4 + j][l15] = accD[mi][j];
  }
#pragma unroll
  for (int q2 = 0; q2 < 2; ++q2) {
    int s = q2 * 512 + t;
    int r = s >> 3, c = s & 7;                  // AB2 row, X-chunk
    int i = i0 + (r & 63);
    int bq = bp * 2 + (r >> 6);
    float4 v0, v1;
    v0.x = v0.y = v0.z = v0.w = 0.f; v1 = v0;
    if (i < NNODE) {
      const float4* xp = (const float4*)(X + ((size_t)bq * NNODE + i) * 64 + c * 8);
      v0 = xp[0]; v1 = xp[1];
    }
    __align__(16) u16 ob[8];
    ob[0] = f2b(v0.x); ob[1] = f2b(v0.y); ob[2] = f2b(v0.z); ob[3] = f2b(v0.w);
    ob[4] = f2b(v1.x); ob[5] = f2b(v1.y); ob[6] = f2b(v1.z); ob[7] = f2b(v1.w);
    *(uint4*)(AB2 + r * 128 + ((c ^ (r & 7)) * 8)) = *(const uint4*)ob;
  }
#pragma unroll
  for (int q2 = 0; q2 < 2; ++q2)
    gload16(W2g + q2 * 4096 + w * 512 + l * 8, W2l + q2 * 4096 + w * 512);
  __syncthreads();

  // ---- P1b: den partial (wc3) accumulate
  if (wc == 3 && l15 < 2) {
#pragma unroll
    for (int mi = 0; mi < 2; ++mi)
#pragma unroll
      for (int j = 0; j < 4; ++j)
        denL[wr * 32 + mi * 16 + g * 4 + j][l15] += accD[mi][j];
  }
  __syncthreads();

  // ---- P2: Zs = acc/den -> AB2 chunks 8..15
#pragma unroll
  for (int mi = 0; mi < 2; ++mi)
#pragma unroll
    for (int ni = 0; ni < 2; ++ni) {
      int col = wc * 32 + ni * 16 + l15;
      int b2 = col >> 6, f = col & 63;
#pragma unroll
      for (int j = 0; j < 4; ++j) {
        int ri = wr * 32 + mi * 16 + g * 4 + j;
        float d = denL[ri][b2];
        float rd = d > 0.f ? 1.f / d : 0.f;
        int R = b2 * 64 + ri;
        AB2[R * 128 + (((8 + (f >> 3)) ^ (R & 7)) * 8) + (f & 7)] = f2b(acc[mi][ni][j] * rd);
      }
    }
  __syncthreads();

  // ---- P3: second gemm: per batch 64x64, K=128
  const int b2w = w >> 2, mf = w & 3;
  f32x4 a2[4];
#pragma unroll
  for (int nf = 0; nf < 4; ++nf) a2[nf] = (f32x4){0.f, 0.f, 0.f, 0.f};
#pragma unroll
  for (int kk = 0; kk < 4; ++kk) {
    int q2 = kk * 4 + g;
    int ra = b2w * 64 + mf * 16 + l15;
    bf16x8 af = *(const bf16x8*)(AB2 + ra * 128 + ((q2 ^ (ra & 7)) * 8));
#pragma unroll
    for (int nf = 0; nf < 4; ++nf) {
      int rb = nf * 16 + l15;
      bf16x8 bfw = *(const bf16x8*)(W2l + rb * 128 + ((q2 ^ (rb & 7)) * 8));
      a2[nf] = __builtin_amdgcn_mfma_f32_16x16x32_bf16(af, bfw, a2[nf], 0, 0, 0);
    }
  }

  // ---- P4: bias + LN + ReLU + guarded store
#pragma unroll
  for (int j = 0; j < 4; ++j) {
    int ri = mf * 16 + g * 4 + j;
    float d = denL[ri][b2w];
    float bnm = d > 0.f ? 1.f : 0.f;
    float v0 = a2[0][j] + bsL[l15]      + bnm * bnL[l15];
    float v1 = a2[1][j] + bsL[l15 + 16] + bnm * bnL[l15 + 16];
    float v2 = a2[2][j] + bsL[l15 + 32] + bnm * bnL[l15 + 32];
    float v3 = a2[3][j] + bsL[l15 + 48] + bnm * bnL[l15 + 48];
    float s1 = v0 + v1 + v2 + v3;
    float s2 = v0 * v0 + v1 * v1 + v2 * v2 + v3 * v3;
    s1 += __shfl_xor(s1, 1); s2 += __shfl_xor(s2, 1);
    s1 += __shfl_xor(s1, 2); s2 += __shfl_xor(s2, 2);
    s1 += __shfl_xor(s1, 4); s2 += __shfl_xor(s2, 4);
    s1 += __shfl_xor(s1, 8); s2 += __shfl_xor(s2, 8);
    float mu = s1 * (1.f / 64.f);
    float var = fmaxf(s2 * (1.f / 64.f) - mu * mu, 0.f);
    float inv = rsqrtf(var + 1e-5f);
    int node = i0 + ri;
    if (node < NNODE) {
      float* op = out + ((size_t)(bp * 2 + b2w) * NNODE + node) * 64;
      op[l15]      = fmaxf((v0 - mu) * inv * gamL[l15]      + betL[l15],      0.f);
      op[l15 + 16] = fmaxf((v1 - mu) * inv * gamL[l15 + 16] + betL[l15 + 16], 0.f);
      op[l15 + 32] = fmaxf((v2 - mu) * inv * gamL[l15 + 32] + betL[l15 + 32], 0.f);
      op[l15 + 48] = fmaxf((v3 - mu) * inv * gamL[l15 + 48] + betL[l15 + 48], 0.f);
    }
  }
}

// ======================= fallback path kernels (round-8, proven) =======================

__global__ __launch_bounds__(256) void k_pre(const int* __restrict__ adj,
                                             const float* __restrict__ Ws,
                                             const float* __restrict__ Wn,
                                             const float* __restrict__ X,
                                             const float* __restrict__ adst,
                                             u16* __restrict__ A,
                                             u16* __restrict__ W2,
                                             u16* __restrict__ Bt) {
  const int bid = blockIdx.x;
  const int t = threadIdx.x;
  if (bid < 364) {                            // A: int32 -> bf16 0/1, padded 896x832
    int idx8 = bid * 256 + t;
    int i = idx8 / 104, j8 = idx8 - i * 104;
    __align__(16) u16 o[8];
    if (i < NNODE && j8 < 98) {
      const int4* ap = (const int4*)(adj + (size_t)i * NNODE + j8 * 8);
      int4 a0 = ap[0], a1 = ap[1];
      o[0] = a0.x ? 0x3F80 : 0; o[1] = a0.y ? 0x3F80 : 0;
      o[2] = a0.z ? 0x3F80 : 0; o[3] = a0.w ? 0x3F80 : 0;
      o[4] = a1.x ? 0x3F80 : 0; o[5] = a1.y ? 0x3F80 : 0;
      o[6] = a1.z ? 0x3F80 : 0; o[7] = a1.w ? 0x3F80 : 0;
    } else {
#pragma unroll
      for (int q = 0; q < 8; ++q) o[q] = 0;
    }
    *(uint4*)(A + (size_t)i * MP + j8 * 8) = *(const uint4*)o;
    return;
  }
  if (bid == 364) {                           // W2: pre-inverse-swizzled bf16 [Ws|Wn]
    int f = t >> 2, cq = t & 3;
#pragma unroll
    for (int q = 0; q < 4; ++q) {
      int c = cq * 4 + q;
      int cs = c ^ (f & 7);
      const float* src = (cs < 8) ? (Ws + f * 64 + cs * 8) : (Wn + f * 64 + (cs - 8) * 8);
      float4 v0 = ((const float4*)src)[0], v1 = ((const float4*)src)[1];
      __align__(16) u16 ob[8];
      ob[0] = f2b(v0.x); ob[1] = f2b(v0.y); ob[2] = f2b(v0.z); ob[3] = f2b(v0.w);
      ob[4] = f2b(v1.x); ob[5] = f2b(v1.y); ob[6] = f2b(v1.z); ob[7] = f2b(v1.w);
      *(uint4*)(W2 + f * 128 + c * 8) = *(const uint4*)ob;
    }
    return;
  }
  __shared__ float Xs[64][68];
  __shared__ float ad[64];
  __shared__ float es[64];
  int bid2 = bid - 365;
  int b = bid2 / 13, jt = bid2 - b * 13;
  int j0 = jt * 64;
  if (b == 64) {
    int row = 4160 + (t >> 2), c = (t & 3) * 16;
    uint4 z; z.x = 0; z.y = 0; z.z = 0; z.w = 0;
    uint4* p = (uint4*)(Bt + (size_t)row * MP + j0 + c);
    p[0] = z; p[1] = z;
    return;
  }
  int jr = t >> 2, cg = t & 3;
  {
    int j = j0 + jr;
    float4 z4; z4.x = 0.f; z4.y = 0.f; z4.z = 0.f; z4.w = 0.f;
    float4 v0 = z4, v1 = z4, v2 = z4, v3 = z4;
    if (j < NNODE) {
      const float4* xp = (const float4*)(X + ((size_t)b * NNODE + j) * 64 + cg * 16);
      v0 = xp[0]; v1 = xp[1]; v2 = xp[2]; v3 = xp[3];
    }
    float4* d = (float4*)&Xs[jr][cg * 16];
    d[0] = v0; d[1] = v1; d[2] = v2; d[3] = v3;
  }
  if (t < 64) ad[t] = adst[t];
  __syncthreads();
  {
    float dot = 0.f;
#pragma unroll
    for (int q = 0; q < 16; ++q) dot += Xs[jr][cg * 16 + q] * ad[cg * 16 + q];
    dot += __shfl_xor(dot, 1);
    dot += __shfl_xor(dot, 2);
    if (cg == 0) es[jr] = (j0 + jr < NNODE) ? __expf(dot) : 0.f;
  }
  __syncthreads();
  {
    int f = t >> 2, jc = (t & 3) * 16;
    __align__(16) u16 ob[16];
#pragma unroll
    for (int q = 0; q < 16; ++q) ob[q] = f2b(es[jc + q] * Xs[jc + q][f]);
    u16* op = Bt + ((size_t)b * 64 + f) * MP + j0 + jc;
    *(uint4*)op = *(const uint4*)ob;
    *(uint4*)(op + 8) = *(const uint4*)(ob + 8);
  }
  if (t < 64) Bt[(size_t)(4096 + b) * MP + j0 + t] = f2b(es[t]);
}

__global__ __launch_bounds__(512, 4) void k_gt(const u16* __restrict__ A,
                                               const u16* __restrict__ Bt,
                                               const u16* __restrict__ W2g,
                                               const float* __restrict__ X,
                                               const float* __restrict__ bs,
                                               const float* __restrict__ bn,
                                               const float* __restrict__ gam,
                                               const float* __restrict__ bet,
                                               float* __restrict__ out) {
  __shared__ __align__(16) u16 lds[2 * BUFU];
  __shared__ float denL[64][2];
  __shared__ float bsL[64], bnL[64], gamL[64], betL[64];
  const int t = threadIdx.x;
  if (t < 64) { bsL[t] = bs[t]; bnL[t] = bn[t]; gamL[t] = gam[t]; betL[t] = bet[t]; }
  phaseB(A, Bt, W2g, X, out, lds, denL, bsL, bnL, gamL, betL, blockIdx.x, t);
}

// ======================= fused single-kernel path =======================

__global__ __launch_bounds__(512, 4) void k_all(const int* __restrict__ adj,
                                                const float* __restrict__ Ws,
                                                const float* __restrict__ Wn,
                                                const float* __restrict__ X,
                                                const float* __restrict__ adst,
                                                const float* __restrict__ bs,
                                                const float* __restrict__ bn,
                                                const float* __restrict__ gam,
                                                const float* __restrict__ bet,
                                                u16* __restrict__ A,
                                                u16* __restrict__ W2g,
                                                u16* __restrict__ Bt,
                                                float* __restrict__ out,
                                                u32* __restrict__ cnt) {
  __shared__ __align__(16) u16 lds[2 * BUFU];   // phase A overlay / phase B dbuf
  __shared__ float denL[64][2];
  __shared__ float bsL[64], bnL[64], gamL[64], betL[64];
  const int bid = blockIdx.x;
  const int t = threadIdx.x;

  // ================= Phase A: prep (distributed over 416 blocks) =================
  {
    int gtid = bid * 512 + t;                   // A-convert: 93184 = 896*104 chunks
    if (gtid < 93184) {
      int i = gtid / 104, j8 = gtid - i * 104;
      __align__(16) u16 o[8];
      if (i < NNODE && j8 < 98) {
        const int4* ap = (const int4*)(adj + (size_t)i * NNODE + j8 * 8);
        int4 a0 = ap[0], a1 = ap[1];
        o[0] = a0.x ? 0x3F80 : 0; o[1] = a0.y ? 0x3F80 : 0;
        o[2] = a0.z ? 0x3F80 : 0; o[3] = a0.w ? 0x3F80 : 0;
        o[4] = a1.x ? 0x3F80 : 0; o[5] = a1.y ? 0x3F80 : 0;
        o[6] = a1.z ? 0x3F80 : 0; o[7] = a1.w ? 0x3F80 : 0;
      } else {
#pragma unroll
        for (int q = 0; q < 8; ++q) o[q] = 0;
      }
      *(uint4*)(A + (size_t)i * MP + j8 * 8) = *(const uint4*)o;
    }
    if (bid == 415 && t < 256) {                // W2 pre-inverse-swizzled
      int f = t >> 2, cq = t & 3;
#pragma unroll
      for (int q = 0; q < 4; ++q) {
        int c = cq * 4 + q;
        int cs = c ^ (f & 7);
        const float* src = (cs < 8) ? (Ws + f * 64 + cs * 8) : (Wn + f * 64 + (cs - 8) * 8);
        float4 v0 = ((const float4*)src)[0], v1 = ((const float4*)src)[1];
        __align__(16) u16 ob[8];
        ob[0] = f2b(v0.x); ob[1] = f2b(v0.y); ob[2] = f2b(v0.z); ob[3] = f2b(v0.w);
        ob[4] = f2b(v1.x); ob[5] = f2b(v1.y); ob[6] = f2b(v1.z); ob[7] = f2b(v1.w);
        *(uint4*)(W2g + f * 128 + c * 8) = *(const uint4*)ob;
      }
    }
    // b1t: 845 tile tasks; 2 sub-blocks of 256 threads; no early returns
    const int sub = t >> 8, t256 = t & 255;
    float* Xs = (float*)((char*)lds + sub * 17920);   // [64][68] f32 overlay
    float* ad = Xs + 64 * 68;
    float* es = ad + 64;
    const int jr = t256 >> 2, cg = t256 & 3;
    for (int base = 0; base < 845; base += 832) {
      int task = base + bid * 2 + sub;
      bool valid = task < 845;
      int b = valid ? task / 13 : 0;
      int jt = valid ? task - b * 13 : 0;
      int j0 = jt * 64;
      if (valid && b == 64) {                   // zero pad rows 4160..4223
        int row = 4160 + (t256 >> 2), c = (t256 & 3) * 16;
        uint4 z; z.x = 0; z.y = 0; z.z = 0; z.w = 0;
        uint4* p = (uint4*)(Bt + (size_t)row * MP + j0 + c);
        p[0] = z; p[1] = z;
      }
      bool work = valid && b < 64;
      if (work) {
        int j = j0 + jr;
        float4 z4; z4.x = 0.f; z4.y = 0.f; z4.z = 0.f; z4.w = 0.f;
        float4 v0 = z4, v1 = z4, v2 = z4, v3 = z4;
        if (j < NNODE) {
          const float4* xp = (const float4*)(X + ((size_t)b * NNODE + j) * 64 + cg * 16);
          v0 = xp[0]; v1 = xp[1]; v2 = xp[2]; v3 = xp[3];
        }
        float4* d = (float4*)&Xs[jr * 68 + cg * 16];
        d[0] = v0; d[1] = v1; d[2] = v2; d[3] = v3;
        if (t256 < 64) ad[t256] = adst[t256];
      }
      __syncthreads();
      if (work) {
        float dot = 0.f;
#pragma unroll
        for (int q = 0; q < 16; ++q) dot += Xs[jr * 68 + cg * 16 + q] * ad[cg * 16 + q];
        dot += __shfl_xor(dot, 1);
        dot += __shfl_xor(dot, 2);
        if (cg == 0) es[jr] = (j0 + jr < NNODE) ? __expf(dot) : 0.f;
      }
      __syncthreads();
      if (work) {
        int f = t256 >> 2, jc = (t256 & 3) * 16;
        __align__(16) u16 ob[16];
#pragma unroll
        for (int q = 0; q < 16; ++q) ob[q] = f2b(es[jc + q] * Xs[(jc + q) * 68 + f]);
        u16* op = Bt + ((size_t)b * 64 + f) * MP + j0 + jc;
        *(uint4*)op = *(const uint4*)ob;
        *(uint4*)(op + 8) = *(const uint4*)(ob + 8);
        if (t256 < 64) Bt[(size_t)(4096 + b) * MP + j0 + t256] = f2b(es[t256]);
      }
      __syncthreads();
    }
  }

  // ================= manual grid barrier (all 416 blocks co-resident) =================
  __threadfence();                              // release phase-A writes (device scope)
  __syncthreads();
  if (t == 0) {
    atomicAdd(cnt, 1u);
    while (atomicAdd(cnt, 0u) < 416u) { __builtin_amdgcn_s_sleep(2); }
  }
  __syncthreads();

  // ================= Phase B =================
  if (t < 64) { bsL[t] = bs[t]; bnL[t] = bn[t]; gamL[t] = gam[t]; betL[t] = bet[t]; }
  phaseB(A, Bt, W2g, X, out, lds, denL, bsL, bnL, gamL, betL, bid, t);
}

extern "C" void kernel_launch(void* const* d_in, const int* in_sizes, int n_in,
                              void* d_out, int out_size, void* d_ws, size_t ws_size,
                              hipStream_t stream) {
  const float* X     = (const float*)d_in[0];
  const int*   adj   = (const int*)d_in[1];
  const float* Wself = (const float*)d_in[2];
  const float* bself = (const float*)d_in[3];
  const float* Wnb   = (const float*)d_in[4];
  const float* bnb   = (const float*)d_in[5];
  // d_in[6] = a_src : cancels in softmax -> unused
  const float* adst  = (const float*)d_in[7];
  // d_in[8] = b_att : cancels in softmax -> unused
  const float* gam   = (const float*)d_in[9];
  const float* bet   = (const float*)d_in[10];
  float* out = (float*)d_out;
  char* ws = (char*)d_ws;

  u16* Apad = (u16*)(ws);                    // 896*832  bf16 = 1,490,944 B
  u16* W2g  = (u16*)(ws + 1490944);          // 64*128   bf16 =    16,384 B
  u16* Bt   = (u16*)(ws + 1507328);          // 4224*832 bf16 = 7,028,736 B
  u32* cnt  = (u32*)(ws + 8536064);          // 4 B barrier counter (end 8,536,068)

  // Host-side, deterministic, capture-safe occupancy check: fused path needs
  // 2 blocks/CU (416 <= 2*256 co-resident) for the spin barrier to be safe.
  int maxb = 0;
  (void)hipOccupancyMaxActiveBlocksPerMultiprocessor(&maxb, k_all, 512, 0);

  if (maxb >= 2) {
    hipMemsetAsync(cnt, 0, 4, stream);
    k_all<<<dim3(416), dim3(512), 0, stream>>>(adj, Wself, Wnb, X, adst,
                                               bself, bnb, gam, bet,
                                               Apad, W2g, Bt, out, cnt);
  } else {
    k_pre<<<dim3(1210), dim3(256), 0, stream>>>(adj, Wself, Wnb, X, adst, Apad, W2g, Bt);
    k_gt <<<dim3(416),  dim3(512), 0, stream>>>(Apad, Bt, W2g, X, bself, bnb, gam, bet, out);
  }
}